// Round 1
// baseline (1307.038 us; speedup 1.0000x reference)
//
#include <hip/hip_runtime.h>
#include <cstdint>

#define DEVINL __device__ __forceinline__

typedef __attribute__((ext_vector_type(4))) float floatx4;
typedef __attribute__((ext_vector_type(8))) __bf16 bf16x8;
typedef __attribute__((ext_vector_type(8))) unsigned short ushortx8;
typedef __attribute__((ext_vector_type(4))) unsigned short ushortx4;

DEVINL unsigned short f2bf(float x) {  // RNE fp32 -> bf16 (finite inputs)
  unsigned int u = __float_as_uint(x);
  u += 0x7fffu + ((u >> 16) & 1u);
  return (unsigned short)(u >> 16);
}
DEVINL float bf2f(unsigned short u) { return __uint_as_float(((unsigned int)u) << 16); }

DEVINL void gload_lds16(const void* g, void* l) {
  __builtin_amdgcn_global_load_lds(
      (const __attribute__((address_space(1))) void*)g,
      (__attribute__((address_space(3))) void*)l, 16, 0, 0);
}

// ---------------------------------------------------------------------------
// C[M x N] = A[M x K] @ Bt[N x K]^T (+epilogue), bf16 MFMA 16x16x32.
// BM=BN=128, BK=32, 256 thr = 4 waves 2x2, wave = 64x64 (4x4 MFMA tiles).
// LDS tiles are stored with a 16B-chunk XOR swizzle: data chunk q of row m
// lives at slot q ^ ((m ^ (m>>2)) & 3).  This turns the 8-way bank conflict
// of the row-stride-64B ds_read_b128 fragment loads into 2-way (free, m136).
// global_load_lds lane l (fixed LDS dst = base + 16*l) therefore sources
// global chunk (l&3) ^ ((l>>2)&3) ^ (l>>4) of row rb + (l>>2).
// EPI==0: C[row*ldc+coloff+col] = acc + bias[col]
// EPI==1: scores epilogue: atomicAdd(scores[row], sum_col tanh(q+bk+acc)*v)
// EPI==2: split-K: atomicAdd(C[...], acc + (z==0 ? bias : 0)); C pre-zeroed
// XSWZ: remap blocks in 64-block chunks so the 8 bx sharing one A-tile get
// the same id%8 (same XCD under round-robin dispatch) -> A staged once/L2.
// ---------------------------------------------------------------------------
template <int EPI, bool ABF16, bool XSWZ>
__global__ __launch_bounds__(256) void gemm_bt(
    const float* __restrict__ Af, const unsigned short* __restrict__ Ab, int lda,
    const unsigned short* __restrict__ Bt, int ldb, int Kc,
    float* __restrict__ C, int ldc, int coloff, const float* __restrict__ bias,
    const float* __restrict__ qv, const float* __restrict__ bkv,
    const float* __restrict__ vvec, float* __restrict__ scores, int Lrows, int Hdim)
{
  __shared__ __align__(16) unsigned short As[128 * 32];
  __shared__ __align__(16) unsigned short Bs[128 * 32];

  const int tid  = threadIdx.x;
  const int wave = tid >> 6;
  const int lane = tid & 63;
  const int qd   = lane >> 4;
  const int lm   = lane & 15;
  const int wr   = wave >> 1;
  const int wc   = wave & 1;

  int bx = blockIdx.x, by = blockIdx.y;
  if (XSWZ) {  // 64-block super-chunks: 8 by x 8 bx, same-by blocks share id%8
    const int id = by * 8 + bx;
    const int c = id >> 6, r = id & 63;
    by = c * 8 + (r & 7);
    bx = r >> 3;
  }
  const long n0 = (long)bx * 128;
  const long m0 = (long)by * 128;
  const long k0base = (long)blockIdx.z * Kc;

  floatx4 acc[4][4];
#pragma unroll
  for (int i = 0; i < 4; ++i)
#pragma unroll
    for (int j = 0; j < 4; ++j)
#pragma unroll
      for (int r = 0; r < 4; ++r) acc[i][j][r] = 0.0f;

  // staging (global_load_lds): lane -> (row, swizzled source chunk)
  const int srow = lane >> 2;
  const int scg  = ((lane & 3) ^ ((lane >> 2) & 3) ^ (lane >> 4)) * 8;  // shorts
  // fp32 A staging: 2 threads/row, thread covers data chunks q0,q0+1
  const int arow = tid >> 1;
  const int q0   = (tid & 1) * 2;
  const int sA   = ((arow & 3) ^ ((arow >> 2) & 3));
  // fragment read swizzle: chunk = qd ^ ((lm ^ (lm>>2)) & 3)
  const int fsw  = (qd ^ ((lm ^ (lm >> 2)) & 3)) * 8;

  const int nIter = Kc >> 5;
  for (int it = 0; it < nIter; ++it) {
    const long k0 = k0base + ((long)it << 5);
    {
      const unsigned short* bsrc = Bt + n0 * (size_t)ldb + k0;
#pragma unroll
      for (int q2 = 0; q2 < 2; ++q2) {
        const int rb = wave * 32 + q2 * 16;   // wave-uniform LDS base
        gload_lds16(bsrc + (size_t)(rb + srow) * ldb + scg, &Bs[rb * 32]);
      }
    }
    if (ABF16) {
      const unsigned short* asrc = Ab + m0 * (size_t)lda + k0;
#pragma unroll
      for (int q2 = 0; q2 < 2; ++q2) {
        const int rb = wave * 32 + q2 * 16;
        gload_lds16(asrc + (size_t)(rb + srow) * lda + scg, &As[rb * 32]);
      }
    } else {
      const float* ap = Af + (m0 + arow) * (size_t)lda + k0 + q0 * 8;
      floatx4 f0 = *(const floatx4*)(ap + 0);
      floatx4 f1 = *(const floatx4*)(ap + 4);
      floatx4 f2 = *(const floatx4*)(ap + 8);
      floatx4 f3 = *(const floatx4*)(ap + 12);
      ushortx8 u0, u1;
#pragma unroll
      for (int e = 0; e < 4; ++e) {
        u0[e]     = f2bf(f0[e]);
        u0[e + 4] = f2bf(f1[e]);
        u1[e]     = f2bf(f2[e]);
        u1[e + 4] = f2bf(f3[e]);
      }
      *(ushortx8*)&As[arow * 32 + (q0 ^ sA) * 8]       = u0;
      *(ushortx8*)&As[arow * 32 + ((q0 + 1) ^ sA) * 8] = u1;
    }
    __syncthreads();

    bf16x8 af[4], bfr[4];
#pragma unroll
    for (int i = 0; i < 4; ++i) {
      const int m = wr * 64 + i * 16 + lm;
      af[i] = *(const bf16x8*)&As[m * 32 + fsw];
    }
#pragma unroll
    for (int j = 0; j < 4; ++j) {
      const int n = wc * 64 + j * 16 + lm;
      bfr[j] = *(const bf16x8*)&Bs[n * 32 + fsw];
    }
#pragma unroll
    for (int i = 0; i < 4; ++i)
#pragma unroll
      for (int j = 0; j < 4; ++j)
        acc[i][j] = __builtin_amdgcn_mfma_f32_16x16x32_bf16(af[i], bfr[j], acc[i][j], 0, 0, 0);
    __syncthreads();
  }

  if (EPI == 0) {
#pragma unroll
    for (int j = 0; j < 4; ++j) {
      const long gc = n0 + wc * 64 + j * 16 + lm;
      const float bj = bias[gc];
#pragma unroll
      for (int i = 0; i < 4; ++i) {
        const long gr0 = m0 + wr * 64 + i * 16 + qd * 4;
#pragma unroll
        for (int r = 0; r < 4; ++r)
          C[(gr0 + r) * (size_t)ldc + coloff + gc] = acc[i][j][r] + bj;
      }
    }
  } else if (EPI == 2) {
#pragma unroll
    for (int j = 0; j < 4; ++j) {
      const long gc = n0 + wc * 64 + j * 16 + lm;
      const float bj = (blockIdx.z == 0) ? bias[gc] : 0.0f;
#pragma unroll
      for (int i = 0; i < 4; ++i) {
        const long gr0 = m0 + wr * 64 + i * 16 + qd * 4;
#pragma unroll
        for (int r = 0; r < 4; ++r)
          atomicAdd(&C[(gr0 + r) * (size_t)ldc + coloff + gc], acc[i][j][r] + bj);
      }
    }
  } else {
    float vj[4], bkj[4];
    long gcj[4];
#pragma unroll
    for (int j = 0; j < 4; ++j) {
      gcj[j] = n0 + wc * 64 + j * 16 + lm;
      vj[j]  = vvec[gcj[j]];
      bkj[j] = bkv[gcj[j]];
    }
#pragma unroll
    for (int i = 0; i < 4; ++i) {
#pragma unroll
      for (int r = 0; r < 4; ++r) {
        const long grow = m0 + wr * 64 + i * 16 + qd * 4 + r;
        const int brow = (int)(grow / Lrows);
        const float* qrow = qv + (size_t)brow * Hdim;
        float s = 0.0f;
#pragma unroll
        for (int j = 0; j < 4; ++j)
          s += tanhf(qrow[gcj[j]] + bkj[j] + acc[i][j][r]) * vj[j];
        s += __shfl_xor(s, 1, 64);
        s += __shfl_xor(s, 2, 64);
        s += __shfl_xor(s, 4, 64);
        s += __shfl_xor(s, 8, 64);
        if (lm == 0) atomicAdd(&scores[grow], s);
      }
    }
  }
}

// --------------------------- prep kernels ----------------------------------
__global__ void transpose_f32_bf16(const float* __restrict__ in,
                                   unsigned short* __restrict__ out, int R, int C) {
  __shared__ float tile[32][33];
  const int c0 = blockIdx.x * 32, r0 = blockIdx.y * 32;
  const int tx = threadIdx.x, ty = threadIdx.y;  // (32,8)
#pragma unroll
  for (int yy = 0; yy < 4; ++yy)
    tile[ty + 8 * yy][tx] = in[(size_t)(r0 + ty + 8 * yy) * C + c0 + tx];
  __syncthreads();
#pragma unroll
  for (int yy = 0; yy < 4; ++yy)
    out[(size_t)(c0 + ty + 8 * yy) * R + r0 + tx] = f2bf(tile[tx][ty + 8 * yy]);
}

__global__ void convert_bf16(const float* __restrict__ in,
                             unsigned short* __restrict__ out, int n4) {
  const int idx = blockIdx.x * blockDim.x + threadIdx.x;
  if (idx < n4) {
    floatx4 f = *(const floatx4*)(in + 4 * (size_t)idx);
    ushortx4 u;
#pragma unroll
    for (int e = 0; e < 4; ++e) u[e] = f2bf(f[e]);
    *(ushortx4*)(out + 4 * (size_t)idx) = u;
  }
}

__global__ void gather_emb(const int* __restrict__ inputs, const float* __restrict__ emb,
                           float* __restrict__ rnn_in, int E, int ldr) {
  const int b = blockIdx.x, t = threadIdx.x;
  const int row = inputs[b];
  for (int e = t; e < E; e += 256)
    rnn_in[(size_t)b * ldr + e] = emb[(size_t)row * E + e];
}

// ----------------------------- softmax over L ------------------------------
__global__ __launch_bounds__(256) void softmax_w(
    const float* __restrict__ scores, const float* __restrict__ bv,
    float* __restrict__ weights, int L)
{
  __shared__ float red[8];
  const int b = blockIdx.x, t = threadIdx.x;
  const int wave = t >> 6;
  float s = (t < L) ? scores[(size_t)b * L + t] + bv[0] : -3.4e38f;
  float m = s;
  for (int o = 32; o > 0; o >>= 1) m = fmaxf(m, __shfl_xor(m, o, 64));
  if ((t & 63) == 0) red[wave] = m;
  __syncthreads();
  m = fmaxf(fmaxf(red[0], red[1]), fmaxf(red[2], red[3]));
  float e = (t < L) ? __expf(s - m) : 0.0f;
  float sum = e;
  for (int o = 32; o > 0; o >>= 1) sum += __shfl_xor(sum, o, 64);
  if ((t & 63) == 0) red[4 + wave] = sum;
  __syncthreads();
  sum = red[4] + red[5] + red[6] + red[7];
  if (t < L) weights[(size_t)b * L + t] = e / sum;
}

// ------------------- context[b,k] = sum_l w[b,l]*keys[b,l,k] ---------------
template <bool KB16>
__global__ __launch_bounds__(256) void context_k(
    const float* __restrict__ weights, const unsigned short* __restrict__ keys16,
    const float* __restrict__ keysf, float* __restrict__ context, int L, int K)
{
  __shared__ float w[256];
  const int b = blockIdx.x, t = threadIdx.x;
  if (t < L) w[t] = weights[(size_t)b * L + t];
  __syncthreads();
  const int col0 = blockIdx.y * 512 + t * 2;
  float a0 = 0.0f, a1 = 0.0f;
  if (KB16) {
    const unsigned short* kp = keys16 + (size_t)b * L * K + col0;
#pragma unroll 4
    for (int l = 0; l < L; ++l) {
      const unsigned int u = *(const unsigned int*)(kp + (size_t)l * K);
      a0 += w[l] * bf2f((unsigned short)(u & 0xffff));
      a1 += w[l] * bf2f((unsigned short)(u >> 16));
    }
  } else {
    const float* kp = keysf + (size_t)b * L * K + col0;
#pragma unroll 4
    for (int l = 0; l < L; ++l) {
      a0 += w[l] * kp[(size_t)l * K];
      a1 += w[l] * kp[(size_t)l * K + 1];
    }
  }
  context[(size_t)b * K + col0]     = a0;
  context[(size_t)b * K + col0 + 1] = a1;
}

// ------------------------------- GRU cell ----------------------------------
__global__ void gru_kernel(const float* __restrict__ gi, const float* __restrict__ gh,
                           const float* __restrict__ hidden, float* __restrict__ hnew, int H) {
  const int idx = blockIdx.x * blockDim.x + threadIdx.x;  // B*H
  const int b = idx / H, h = idx % H;
  const size_t base = (size_t)b * 3 * H;
  const float ir = gi[base + h], iz = gi[base + H + h], inn = gi[base + 2 * H + h];
  const float hr = gh[base + h], hz = gh[base + H + h], hn = gh[base + 2 * H + h];
  const float r = 1.0f / (1.0f + __expf(-(ir + hr)));
  const float z = 1.0f / (1.0f + __expf(-(iz + hz)));
  const float n = tanhf(inn + r * hn);
  const float hv = hidden[(size_t)b * H + h];
  hnew[(size_t)b * H + h] = (1.0f - z) * n + z * hv;
}

// ---------------------------------------------------------------------------
extern "C" void kernel_launch(void* const* d_in, const int* in_sizes, int n_in,
                              void* d_out, int out_size, void* d_ws, size_t ws_size,
                              hipStream_t stream) {
  constexpr int V = 32000, E = 512, H = 1024, KD = 2048, L = 196, B = 256;
  constexpr int G3 = 3 * H;   // 3072
  constexpr int EH = E + H;   // 1536

  const int*   inputs = (const int*)d_in[0];
  const float* hidden = (const float*)d_in[1];
  const float* keys   = (const float*)d_in[2];
  const float* emb    = (const float*)d_in[3];
  const float* Wq     = (const float*)d_in[4];
  const float* bq     = (const float*)d_in[5];
  const float* Wk     = (const float*)d_in[6];
  const float* bk     = (const float*)d_in[7];
  const float* vvec   = (const float*)d_in[8];
  const float* bv     = (const float*)d_in[9];
  const float* fc0_W  = (const float*)d_in[10];
  const float* fc0_b  = (const float*)d_in[11];
  const float* W_ih   = (const float*)d_in[12];
  const float* W_hh   = (const float*)d_in[13];
  const float* b_ih   = (const float*)d_in[14];
  const float* b_hh   = (const float*)d_in[15];
  const float* fc1_W  = (const float*)d_in[16];
  const float* fc1_b  = (const float*)d_in[17];

  float* logits  = (float*)d_out;
  float* hnew    = logits + (size_t)B * V;
  float* weights = hnew + (size_t)B * H;

  char* ws = (char*)d_ws;
  size_t off = 0;
  auto bump = [&off](size_t bytes) {
    size_t p = off;
    off += (bytes + 255) & ~(size_t)255;
    return p;
  };
  unsigned short* WqT   = (unsigned short*)(ws + bump((size_t)H * H * 2));
  unsigned short* WkT   = (unsigned short*)(ws + bump((size_t)H * KD * 2));
  unsigned short* fc0T  = (unsigned short*)(ws + bump((size_t)H * KD * 2));
  unsigned short* fc1T  = (unsigned short*)(ws + bump((size_t)V * H * 2));
  unsigned short* Wih16 = (unsigned short*)(ws + bump((size_t)G3 * EH * 2));
  unsigned short* Whh16 = (unsigned short*)(ws + bump((size_t)G3 * H * 2));
  float* qbuf    = (float*)(ws + bump((size_t)B * H * 4));
  float* scoresb = (float*)(ws + bump((size_t)B * L * 4));
  float* context = (float*)(ws + bump((size_t)B * KD * 4));
  float* rnn_in  = (float*)(ws + bump((size_t)B * EH * 4));
  float* gi      = (float*)(ws + bump((size_t)B * G3 * 4));
  float* gh      = (float*)(ws + bump((size_t)B * G3 * 4));
  unsigned short* keys16 = (unsigned short*)(ws + bump((size_t)B * L * KD * 2));
  const bool useK16 = (off <= ws_size);  // constant across calls -> graph-safe

  // split-K targets must start from zero (ws is re-poisoned before each call)
  hipMemsetAsync(scoresb, 0, (size_t)B * L * 4, stream);
  hipMemsetAsync(qbuf, 0, (size_t)B * H * 4, stream);
  hipMemsetAsync(rnn_in, 0, (size_t)B * EH * 4, stream);
  hipMemsetAsync(gi, 0, (size_t)B * G3 * 4, stream);
  hipMemsetAsync(gh, 0, (size_t)B * G3 * 4, stream);

  const dim3 tb(32, 8);
  transpose_f32_bf16<<<dim3(H / 32, H / 32), tb, 0, stream>>>(Wq, WqT, H, H);
  transpose_f32_bf16<<<dim3(H / 32, KD / 32), tb, 0, stream>>>(Wk, WkT, KD, H);
  transpose_f32_bf16<<<dim3(H / 32, KD / 32), tb, 0, stream>>>(fc0_W, fc0T, KD, H);
  transpose_f32_bf16<<<dim3(V / 32, H / 32), tb, 0, stream>>>(fc1_W, fc1T, H, V);
  convert_bf16<<<(G3 * EH / 4 + 255) / 256, 256, 0, stream>>>(W_ih, Wih16, G3 * EH / 4);
  convert_bf16<<<(G3 * H / 4 + 255) / 256, 256, 0, stream>>>(W_hh, Whh16, G3 * H / 4);
  if (useK16) {
    const int n4 = B * L * KD / 4;
    convert_bf16<<<(n4 + 255) / 256, 256, 0, stream>>>(keys, keys16, n4);
  }

  gather_emb<<<B, 256, 0, stream>>>(inputs, emb, rnn_in, E, EH);

  // q = hidden @ Wq + bq   (split-K x4 -> 64 blocks instead of 16)
  gemm_bt<2, false, false><<<dim3(H / 128, B / 128, 4), 256, 0, stream>>>(
      hidden, nullptr, H, WqT, H, H / 4, qbuf, H, 0, bq,
      nullptr, nullptr, nullptr, nullptr, 0, 0);

  // scores[b*L+l] = tanh(q[b]+bk+keys[b,l]@Wk) . v   (the 210 GFLOP GEMM)
  if (useK16)
    gemm_bt<1, true, true><<<dim3(H / 128, (B * L) / 128, 1), 256, 0, stream>>>(
        nullptr, keys16, KD, WkT, KD, KD, nullptr, 0, 0, nullptr,
        qbuf, bk, vvec, scoresb, L, H);
  else
    gemm_bt<1, false, true><<<dim3(H / 128, (B * L) / 128, 1), 256, 0, stream>>>(
        keys, nullptr, KD, WkT, KD, KD, nullptr, 0, 0, nullptr,
        qbuf, bk, vvec, scoresb, L, H);

  softmax_w<<<B, 256, 0, stream>>>(scoresb, bv, weights, L);

  if (useK16)
    context_k<true><<<dim3(B, KD / 512), 256, 0, stream>>>(weights, keys16, nullptr,
                                                           context, L, KD);
  else
    context_k<false><<<dim3(B, KD / 512), 256, 0, stream>>>(weights, nullptr, keys,
                                                            context, L, KD);

  // rnn_in[:, E:] = context @ fc0_W + fc0_b   (split-K x4)
  gemm_bt<2, false, false><<<dim3(H / 128, B / 128, 4), 256, 0, stream>>>(
      context, nullptr, KD, fc0T, KD, KD / 4, rnn_in, EH, E, fc0_b,
      nullptr, nullptr, nullptr, nullptr, 0, 0);

  // gi = rnn_in @ W_ih^T + b_ih   (split-K x4)
  gemm_bt<2, false, false><<<dim3(G3 / 128, B / 128, 4), 256, 0, stream>>>(
      rnn_in, nullptr, EH, Wih16, EH, EH / 4, gi, G3, 0, b_ih,
      nullptr, nullptr, nullptr, nullptr, 0, 0);

  // gh = hidden @ W_hh^T + b_hh   (split-K x4)
  gemm_bt<2, false, false><<<dim3(G3 / 128, B / 128, 4), 256, 0, stream>>>(
      hidden, nullptr, H, Whh16, H, H / 4, gh, G3, 0, b_hh,
      nullptr, nullptr, nullptr, nullptr, 0, 0);

  gru_kernel<<<(B * H) / 256, 256, 0, stream>>>(gi, gh, hidden, hnew, H);

  // logits = h_new @ fc1_W + fc1_b  (500 blocks, no split needed)
  gemm_bt<0, false, false><<<dim3(V / 128, B / 128, 1), 256, 0, stream>>>(
      hnew, nullptr, H, fc1T, H, H, logits, V, 0, fc1_b,
      nullptr, nullptr, nullptr, nullptr, 0, 0);
}

// Round 2
// 1267.079 us; speedup vs baseline: 1.0315x; 1.0315x over previous
//
#include <hip/hip_runtime.h>
#include <cstdint>

#define DEVINL __device__ __forceinline__

typedef __attribute__((ext_vector_type(4))) float floatx4;
typedef __attribute__((ext_vector_type(8))) __bf16 bf16x8;
typedef __attribute__((ext_vector_type(8))) unsigned short ushortx8;
typedef __attribute__((ext_vector_type(4))) unsigned short ushortx4;

DEVINL unsigned short f2bf(float x) {  // RNE fp32 -> bf16 (finite inputs)
  unsigned int u = __float_as_uint(x);
  u += 0x7fffu + ((u >> 16) & 1u);
  return (unsigned short)(u >> 16);
}
DEVINL float bf2f(unsigned short u) { return __uint_as_float(((unsigned int)u) << 16); }

DEVINL float fast_tanh(float x) {  // branch-free: 1 - 2/(e^{2x}+1); exact at +-inf
  return 1.0f - 2.0f / (__expf(2.0f * x) + 1.0f);
}

DEVINL void gload_lds16(const void* g, void* l) {
  __builtin_amdgcn_global_load_lds(
      (const __attribute__((address_space(1))) void*)g,
      (__attribute__((address_space(3))) void*)l, 16, 0, 0);
}

// ---------------------------------------------------------------------------
// C[M x N] = A[M x K] @ Bt[N x K]^T (+epilogue), bf16 MFMA 16x16x32.
// BM=BN=128, BK=32, 256 thr = 4 waves 2x2, wave = 64x64 (4x4 MFMA tiles).
// LDS tiles are stored with a 16B-chunk XOR swizzle: data chunk q of row m
// lives at slot q ^ ((m ^ (m>>2)) & 3).  This turns the 8-way bank conflict
// of the row-stride-64B ds_read_b128 fragment loads into 2-way (free, m136).
// global_load_lds lane l (fixed LDS dst = base + 16*l) therefore sources
// global chunk (l&3) ^ ((l>>2)&3) ^ (l>>4) of row rb + (l>>2).
// EPI==0: C[row*ldc+coloff+col] = acc + bias[col]
// EPI==1: scores epilogue: atomicAdd(scores[row], sum_col tanh(q+bk+acc)*v)
//         (magic-div by Lrows==196, fast tanh — epilogue was ~30% of kernel
//          time as s64-div + libm tanhf VALU work, R1 fix)
// EPI==2: split-K: atomicAdd(C[...], acc + (z==0 ? bias : 0)); C pre-zeroed
// XSWZ: remap blocks in 64-block chunks so the 8 bx sharing one A-tile get
// the same id%8 (same XCD under round-robin dispatch) -> A staged once/L2.
// ---------------------------------------------------------------------------
template <int EPI, bool ABF16, bool XSWZ>
__global__ __launch_bounds__(256) void gemm_bt(
    const float* __restrict__ Af, const unsigned short* __restrict__ Ab, int lda,
    const unsigned short* __restrict__ Bt, int ldb, int Kc,
    float* __restrict__ C, int ldc, int coloff, const float* __restrict__ bias,
    const float* __restrict__ qv, const float* __restrict__ bkv,
    const float* __restrict__ vvec, float* __restrict__ scores, int Lrows, int Hdim)
{
  __shared__ __align__(16) unsigned short As[128 * 32];
  __shared__ __align__(16) unsigned short Bs[128 * 32];

  const int tid  = threadIdx.x;
  const int wave = tid >> 6;
  const int lane = tid & 63;
  const int qd   = lane >> 4;
  const int lm   = lane & 15;
  const int wr   = wave >> 1;
  const int wc   = wave & 1;

  int bx = blockIdx.x, by = blockIdx.y;
  if (XSWZ) {  // 64-block super-chunks: 8 by x 8 bx, same-by blocks share id%8
    const int id = by * 8 + bx;
    const int c = id >> 6, r = id & 63;
    by = c * 8 + (r & 7);
    bx = r >> 3;
  }
  const long n0 = (long)bx * 128;
  const long m0 = (long)by * 128;
  const long k0base = (long)blockIdx.z * Kc;

  floatx4 acc[4][4];
#pragma unroll
  for (int i = 0; i < 4; ++i)
#pragma unroll
    for (int j = 0; j < 4; ++j)
#pragma unroll
      for (int r = 0; r < 4; ++r) acc[i][j][r] = 0.0f;

  // staging (global_load_lds): lane -> (row, swizzled source chunk)
  const int srow = lane >> 2;
  const int scg  = ((lane & 3) ^ ((lane >> 2) & 3) ^ (lane >> 4)) * 8;  // shorts
  // fp32 A staging: 2 threads/row, thread covers data chunks q0,q0+1
  const int arow = tid >> 1;
  const int q0   = (tid & 1) * 2;
  const int sA   = ((arow & 3) ^ ((arow >> 2) & 3));
  // fragment read swizzle: chunk = qd ^ ((lm ^ (lm>>2)) & 3)
  const int fsw  = (qd ^ ((lm ^ (lm >> 2)) & 3)) * 8;

  const int nIter = Kc >> 5;
  for (int it = 0; it < nIter; ++it) {
    const long k0 = k0base + ((long)it << 5);
    {
      const unsigned short* bsrc = Bt + n0 * (size_t)ldb + k0;
#pragma unroll
      for (int q2 = 0; q2 < 2; ++q2) {
        const int rb = wave * 32 + q2 * 16;   // wave-uniform LDS base
        gload_lds16(bsrc + (size_t)(rb + srow) * ldb + scg, &Bs[rb * 32]);
      }
    }
    if (ABF16) {
      const unsigned short* asrc = Ab + m0 * (size_t)lda + k0;
#pragma unroll
      for (int q2 = 0; q2 < 2; ++q2) {
        const int rb = wave * 32 + q2 * 16;
        gload_lds16(asrc + (size_t)(rb + srow) * lda + scg, &As[rb * 32]);
      }
    } else {
      const float* ap = Af + (m0 + arow) * (size_t)lda + k0 + q0 * 8;
      floatx4 f0 = *(const floatx4*)(ap + 0);
      floatx4 f1 = *(const floatx4*)(ap + 4);
      floatx4 f2 = *(const floatx4*)(ap + 8);
      floatx4 f3 = *(const floatx4*)(ap + 12);
      ushortx8 u0, u1;
#pragma unroll
      for (int e = 0; e < 4; ++e) {
        u0[e]     = f2bf(f0[e]);
        u0[e + 4] = f2bf(f1[e]);
        u1[e]     = f2bf(f2[e]);
        u1[e + 4] = f2bf(f3[e]);
      }
      *(ushortx8*)&As[arow * 32 + (q0 ^ sA) * 8]       = u0;
      *(ushortx8*)&As[arow * 32 + ((q0 + 1) ^ sA) * 8] = u1;
    }
    __syncthreads();

    bf16x8 af[4], bfr[4];
#pragma unroll
    for (int i = 0; i < 4; ++i) {
      const int m = wr * 64 + i * 16 + lm;
      af[i] = *(const bf16x8*)&As[m * 32 + fsw];
    }
#pragma unroll
    for (int j = 0; j < 4; ++j) {
      const int n = wc * 64 + j * 16 + lm;
      bfr[j] = *(const bf16x8*)&Bs[n * 32 + fsw];
    }
#pragma unroll
    for (int i = 0; i < 4; ++i)
#pragma unroll
      for (int j = 0; j < 4; ++j)
        acc[i][j] = __builtin_amdgcn_mfma_f32_16x16x32_bf16(af[i], bfr[j], acc[i][j], 0, 0, 0);
    __syncthreads();
  }

  if (EPI == 0) {
#pragma unroll
    for (int j = 0; j < 4; ++j) {
      const long gc = n0 + wc * 64 + j * 16 + lm;
      const float bj = bias[gc];
#pragma unroll
      for (int i = 0; i < 4; ++i) {
        const long gr0 = m0 + wr * 64 + i * 16 + qd * 4;
#pragma unroll
        for (int r = 0; r < 4; ++r)
          C[(gr0 + r) * (size_t)ldc + coloff + gc] = acc[i][j][r] + bj;
      }
    }
  } else if (EPI == 2) {
#pragma unroll
    for (int j = 0; j < 4; ++j) {
      const long gc = n0 + wc * 64 + j * 16 + lm;
      const float bj = (blockIdx.z == 0) ? bias[gc] : 0.0f;
#pragma unroll
      for (int i = 0; i < 4; ++i) {
        const long gr0 = m0 + wr * 64 + i * 16 + qd * 4;
#pragma unroll
        for (int r = 0; r < 4; ++r)
          atomicAdd(&C[(gr0 + r) * (size_t)ldc + coloff + gc], acc[i][j][r] + bj);
      }
    }
  } else {
    // R1: all-int32 index math, exact magic-div for /196, fast tanh.
    float vj[4], bkj[4];
    int gcj[4];
#pragma unroll
    for (int j = 0; j < 4; ++j) {
      gcj[j] = (int)(n0 + wc * 64 + j * 16 + lm);
      vj[j]  = vvec[gcj[j]];
      bkj[j] = bkv[gcj[j]];
    }
    const int m0i = (int)m0;
#pragma unroll
    for (int i = 0; i < 4; ++i) {
#pragma unroll
      for (int r = 0; r < 4; ++r) {
        const int grow = m0i + wr * 64 + i * 16 + qd * 4 + r;
        // grow/196 exact for grow < 50176: m=ceil(2^24/196)=85599, e=188,
        // e*n_max = 188*50175 < 2^24.  Generic fallback for other L.
        int brow;
        if (Lrows == 196) brow = (int)((unsigned)(grow * 85599u) >> 24);
        else              brow = grow / Lrows;
        const float* qrow = qv + (size_t)brow * Hdim;
        float s = 0.0f;
#pragma unroll
        for (int j = 0; j < 4; ++j)
          s += fast_tanh(qrow[gcj[j]] + bkj[j] + acc[i][j][r]) * vj[j];
        s += __shfl_xor(s, 1, 64);
        s += __shfl_xor(s, 2, 64);
        s += __shfl_xor(s, 4, 64);
        s += __shfl_xor(s, 8, 64);
        if (lm == 0) atomicAdd(&scores[grow], s);
      }
    }
  }
}

// --------------------------- prep kernels ----------------------------------
__global__ void transpose_f32_bf16(const float* __restrict__ in,
                                   unsigned short* __restrict__ out, int R, int C) {
  __shared__ float tile[32][33];
  const int c0 = blockIdx.x * 32, r0 = blockIdx.y * 32;
  const int tx = threadIdx.x, ty = threadIdx.y;  // (32,8)
#pragma unroll
  for (int yy = 0; yy < 4; ++yy)
    tile[ty + 8 * yy][tx] = in[(size_t)(r0 + ty + 8 * yy) * C + c0 + tx];
  __syncthreads();
#pragma unroll
  for (int yy = 0; yy < 4; ++yy)
    out[(size_t)(c0 + ty + 8 * yy) * R + r0 + tx] = f2bf(tile[tx][ty + 8 * yy]);
}

__global__ void convert_bf16(const float* __restrict__ in,
                             unsigned short* __restrict__ out, int n4) {
  const int idx = blockIdx.x * blockDim.x + threadIdx.x;
  if (idx < n4) {
    floatx4 f = *(const floatx4*)(in + 4 * (size_t)idx);
    ushortx4 u;
#pragma unroll
    for (int e = 0; e < 4; ++e) u[e] = f2bf(f[e]);
    *(ushortx4*)(out + 4 * (size_t)idx) = u;
  }
}

__global__ void gather_emb(const int* __restrict__ inputs, const float* __restrict__ emb,
                           float* __restrict__ rnn_in, int E, int ldr) {
  const int b = blockIdx.x, t = threadIdx.x;
  const int row = inputs[b];
  for (int e = t; e < E; e += 256)
    rnn_in[(size_t)b * ldr + e] = emb[(size_t)row * E + e];
}

// ----------------------------- softmax over L ------------------------------
__global__ __launch_bounds__(256) void softmax_w(
    const float* __restrict__ scores, const float* __restrict__ bv,
    float* __restrict__ weights, int L)
{
  __shared__ float red[8];
  const int b = blockIdx.x, t = threadIdx.x;
  const int wave = t >> 6;
  float s = (t < L) ? scores[(size_t)b * L + t] + bv[0] : -3.4e38f;
  float m = s;
  for (int o = 32; o > 0; o >>= 1) m = fmaxf(m, __shfl_xor(m, o, 64));
  if ((t & 63) == 0) red[wave] = m;
  __syncthreads();
  m = fmaxf(fmaxf(red[0], red[1]), fmaxf(red[2], red[3]));
  float e = (t < L) ? __expf(s - m) : 0.0f;
  float sum = e;
  for (int o = 32; o > 0; o >>= 1) sum += __shfl_xor(sum, o, 64);
  if ((t & 63) == 0) red[4 + wave] = sum;
  __syncthreads();
  sum = red[4] + red[5] + red[6] + red[7];
  if (t < L) weights[(size_t)b * L + t] = e / sum;
}

// ------------------- context[b,k] = sum_l w[b,l]*keys[b,l,k] ---------------
template <bool KB16>
__global__ __launch_bounds__(256) void context_k(
    const float* __restrict__ weights, const unsigned short* __restrict__ keys16,
    const float* __restrict__ keysf, float* __restrict__ context, int L, int K)
{
  __shared__ float w[256];
  const int b = blockIdx.x, t = threadIdx.x;
  if (t < L) w[t] = weights[(size_t)b * L + t];
  __syncthreads();
  const int col0 = blockIdx.y * 512 + t * 2;
  float a0 = 0.0f, a1 = 0.0f;
  if (KB16) {
    const unsigned short* kp = keys16 + (size_t)b * L * K + col0;
#pragma unroll 4
    for (int l = 0; l < L; ++l) {
      const unsigned int u = *(const unsigned int*)(kp + (size_t)l * K);
      a0 += w[l] * bf2f((unsigned short)(u & 0xffff));
      a1 += w[l] * bf2f((unsigned short)(u >> 16));
    }
  } else {
    const float* kp = keysf + (size_t)b * L * K + col0;
#pragma unroll 4
    for (int l = 0; l < L; ++l) {
      a0 += w[l] * kp[(size_t)l * K];
      a1 += w[l] * kp[(size_t)l * K + 1];
    }
  }
  context[(size_t)b * K + col0]     = a0;
  context[(size_t)b * K + col0 + 1] = a1;
}

// ------------------------------- GRU cell ----------------------------------
__global__ void gru_kernel(const float* __restrict__ gi, const float* __restrict__ gh,
                           const float* __restrict__ hidden, float* __restrict__ hnew, int H) {
  const int idx = blockIdx.x * blockDim.x + threadIdx.x;  // B*H
  const int b = idx / H, h = idx % H;
  const size_t base = (size_t)b * 3 * H;
  const float ir = gi[base + h], iz = gi[base + H + h], inn = gi[base + 2 * H + h];
  const float hr = gh[base + h], hz = gh[base + H + h], hn = gh[base + 2 * H + h];
  const float r = 1.0f / (1.0f + __expf(-(ir + hr)));
  const float z = 1.0f / (1.0f + __expf(-(iz + hz)));
  const float n = tanhf(inn + r * hn);
  const float hv = hidden[(size_t)b * H + h];
  hnew[(size_t)b * H + h] = (1.0f - z) * n + z * hv;
}

// ---------------------------------------------------------------------------
extern "C" void kernel_launch(void* const* d_in, const int* in_sizes, int n_in,
                              void* d_out, int out_size, void* d_ws, size_t ws_size,
                              hipStream_t stream) {
  constexpr int V = 32000, E = 512, H = 1024, KD = 2048, L = 196, B = 256;
  constexpr int G3 = 3 * H;   // 3072
  constexpr int EH = E + H;   // 1536

  const int*   inputs = (const int*)d_in[0];
  const float* hidden = (const float*)d_in[1];
  const float* keys   = (const float*)d_in[2];
  const float* emb    = (const float*)d_in[3];
  const float* Wq     = (const float*)d_in[4];
  const float* bq     = (const float*)d_in[5];
  const float* Wk     = (const float*)d_in[6];
  const float* bk     = (const float*)d_in[7];
  const float* vvec   = (const float*)d_in[8];
  const float* bv     = (const float*)d_in[9];
  const float* fc0_W  = (const float*)d_in[10];
  const float* fc0_b  = (const float*)d_in[11];
  const float* W_ih   = (const float*)d_in[12];
  const float* W_hh   = (const float*)d_in[13];
  const float* b_ih   = (const float*)d_in[14];
  const float* b_hh   = (const float*)d_in[15];
  const float* fc1_W  = (const float*)d_in[16];
  const float* fc1_b  = (const float*)d_in[17];

  float* logits  = (float*)d_out;
  float* hnew    = logits + (size_t)B * V;
  float* weights = hnew + (size_t)B * H;

  char* ws = (char*)d_ws;
  size_t off = 0;
  auto bump = [&off](size_t bytes) {
    size_t p = off;
    off += (bytes + 255) & ~(size_t)255;
    return p;
  };
  unsigned short* WqT   = (unsigned short*)(ws + bump((size_t)H * H * 2));
  unsigned short* WkT   = (unsigned short*)(ws + bump((size_t)H * KD * 2));
  unsigned short* fc0T  = (unsigned short*)(ws + bump((size_t)H * KD * 2));
  unsigned short* fc1T  = (unsigned short*)(ws + bump((size_t)V * H * 2));
  unsigned short* Wih16 = (unsigned short*)(ws + bump((size_t)G3 * EH * 2));
  unsigned short* Whh16 = (unsigned short*)(ws + bump((size_t)G3 * H * 2));
  float* qbuf    = (float*)(ws + bump((size_t)B * H * 4));
  float* scoresb = (float*)(ws + bump((size_t)B * L * 4));
  float* context = (float*)(ws + bump((size_t)B * KD * 4));
  float* rnn_in  = (float*)(ws + bump((size_t)B * EH * 4));
  float* gi      = (float*)(ws + bump((size_t)B * G3 * 4));
  float* gh      = (float*)(ws + bump((size_t)B * G3 * 4));
  unsigned short* keys16 = (unsigned short*)(ws + bump((size_t)B * L * KD * 2));
  const bool useK16 = (off <= ws_size);  // constant across calls -> graph-safe

  // split-K targets must start from zero (ws is re-poisoned before each call)
  hipMemsetAsync(scoresb, 0, (size_t)B * L * 4, stream);
  hipMemsetAsync(qbuf, 0, (size_t)B * H * 4, stream);
  hipMemsetAsync(rnn_in, 0, (size_t)B * EH * 4, stream);
  hipMemsetAsync(gi, 0, (size_t)B * G3 * 4, stream);
  hipMemsetAsync(gh, 0, (size_t)B * G3 * 4, stream);

  const dim3 tb(32, 8);
  transpose_f32_bf16<<<dim3(H / 32, H / 32), tb, 0, stream>>>(Wq, WqT, H, H);
  transpose_f32_bf16<<<dim3(H / 32, KD / 32), tb, 0, stream>>>(Wk, WkT, KD, H);
  transpose_f32_bf16<<<dim3(H / 32, KD / 32), tb, 0, stream>>>(fc0_W, fc0T, KD, H);
  transpose_f32_bf16<<<dim3(V / 32, H / 32), tb, 0, stream>>>(fc1_W, fc1T, H, V);
  convert_bf16<<<(G3 * EH / 4 + 255) / 256, 256, 0, stream>>>(W_ih, Wih16, G3 * EH / 4);
  convert_bf16<<<(G3 * H / 4 + 255) / 256, 256, 0, stream>>>(W_hh, Whh16, G3 * H / 4);
  if (useK16) {
    const int n4 = B * L * KD / 4;
    convert_bf16<<<(n4 + 255) / 256, 256, 0, stream>>>(keys, keys16, n4);
  }

  gather_emb<<<B, 256, 0, stream>>>(inputs, emb, rnn_in, E, EH);

  // q = hidden @ Wq + bq   (split-K x4 -> 64 blocks instead of 16)
  gemm_bt<2, false, false><<<dim3(H / 128, B / 128, 4), 256, 0, stream>>>(
      hidden, nullptr, H, WqT, H, H / 4, qbuf, H, 0, bq,
      nullptr, nullptr, nullptr, nullptr, 0, 0);

  // scores[b*L+l] = tanh(q[b]+bk+keys[b,l]@Wk) . v   (the 210 GFLOP GEMM)
  if (useK16)
    gemm_bt<1, true, true><<<dim3(H / 128, (B * L) / 128, 1), 256, 0, stream>>>(
        nullptr, keys16, KD, WkT, KD, KD, nullptr, 0, 0, nullptr,
        qbuf, bk, vvec, scoresb, L, H);
  else
    gemm_bt<1, false, true><<<dim3(H / 128, (B * L) / 128, 1), 256, 0, stream>>>(
        keys, nullptr, KD, WkT, KD, KD, nullptr, 0, 0, nullptr,
        qbuf, bk, vvec, scoresb, L, H);

  softmax_w<<<B, 256, 0, stream>>>(scoresb, bv, weights, L);

  if (useK16)
    context_k<true><<<dim3(B, KD / 512), 256, 0, stream>>>(weights, keys16, nullptr,
                                                           context, L, KD);
  else
    context_k<false><<<dim3(B, KD / 512), 256, 0, stream>>>(weights, nullptr, keys,
                                                            context, L, KD);

  // rnn_in[:, E:] = context @ fc0_W + fc0_b   (split-K x4)
  gemm_bt<2, false, false><<<dim3(H / 128, B / 128, 4), 256, 0, stream>>>(
      context, nullptr, KD, fc0T, KD, KD / 4, rnn_in, EH, E, fc0_b,
      nullptr, nullptr, nullptr, nullptr, 0, 0);

  // gi = rnn_in @ W_ih^T + b_ih   (split-K x4)
  gemm_bt<2, false, false><<<dim3(G3 / 128, B / 128, 4), 256, 0, stream>>>(
      rnn_in, nullptr, EH, Wih16, EH, EH / 4, gi, G3, 0, b_ih,
      nullptr, nullptr, nullptr, nullptr, 0, 0);

  // gh = hidden @ W_hh^T + b_hh   (split-K x4)
  gemm_bt<2, false, false><<<dim3(G3 / 128, B / 128, 4), 256, 0, stream>>>(
      hidden, nullptr, H, Whh16, H, H / 4, gh, G3, 0, b_hh,
      nullptr, nullptr, nullptr, nullptr, 0, 0);

  gru_kernel<<<(B * H) / 256, 256, 0, stream>>>(gi, gh, hidden, hnew, H);

  // logits = h_new @ fc1_W + fc1_b  (500 blocks, no split needed)
  gemm_bt<0, false, false><<<dim3(V / 128, B / 128, 1), 256, 0, stream>>>(
      hnew, nullptr, H, fc1T, H, H, logits, V, 0, fc1_b,
      nullptr, nullptr, nullptr, nullptr, 0, 0);
}

// Round 3
// 1204.253 us; speedup vs baseline: 1.0854x; 1.0522x over previous
//
#include <hip/hip_runtime.h>
#include <cstdint>

#define DEVINL __device__ __forceinline__

typedef __attribute__((ext_vector_type(4))) float floatx4;
typedef __attribute__((ext_vector_type(8))) __bf16 bf16x8;
typedef __attribute__((ext_vector_type(8))) unsigned short ushortx8;
typedef __attribute__((ext_vector_type(4))) unsigned short ushortx4;

DEVINL unsigned short f2bf(float x) {  // RNE fp32 -> bf16 (finite inputs)
  unsigned int u = __float_as_uint(x);
  u += 0x7fffu + ((u >> 16) & 1u);
  return (unsigned short)(u >> 16);
}
DEVINL float bf2f(unsigned short u) { return __uint_as_float(((unsigned int)u) << 16); }

DEVINL float fast_tanh(float x) {  // branch-free: 1 - 2/(e^{2x}+1); exact at +-inf
  return 1.0f - 2.0f / (__expf(2.0f * x) + 1.0f);
}

DEVINL void gload_lds16(const void* g, void* l) {
  __builtin_amdgcn_global_load_lds(
      (const __attribute__((address_space(1))) void*)g,
      (__attribute__((address_space(3))) void*)l, 16, 0, 0);
}

// ===========================================================================
// 8-phase 256x256 BK=64 scores GEMM (T2+T3+T4+T5 per catalog).
// A = keys16 [M=50176][K=2048] bf16, B = WkT [N=1024][K=2048] bf16.
// 512 thr = 8 waves (2M x 4N); per-wave output 128x64 = acc[8][4] f32x4.
// LDS 128 KiB: 2 buffers x 4 units (A0,A1,B0,B1) x [128 rows][64 cols] bf16.
// Swizzle: 16B chunk slot s of row r holds data chunk s ^ (r&7) -> ds_read
// <=2-way bank conflict (free); gload_lds dst is lane-linear, src pre-swizzled
// (chunk = (l&7)^(l>>3), lane-only constant).
// Phases per K-tile t (quadrants of per-wave output, A-half in regs, both
// B-halves held):
//   ph0: read A(mh0,8xb128)+B(nh0,4); stage A1(t+1); Q(0,0)
//   ph1: read B(nh1,4);               Q(0,1)
//   ph2: read A(mh1,8); stage B0(t+2); Q(1,0)
//   ph3: stage B1(t+2)+A0(t+2);        Q(1,1); s_waitcnt vmcnt(6); barrier
// Steady state: 3 half-tile units (6 loads) in flight across the K-tile
// boundary -> the wait is counted, never a drain; each unit has ~4 phases of
// MFMA+LDS latency to land (covers HBM ~900cy for the always-cold A stream).
// WAR safety: every staged unit's target region finished its ds_reads at
// least one closing barrier before the stage issues (verified per-region).
// Epilogue: scores[row] += sum_n tanh(q[row/196][n]+bk[n]+acc)*v[n],
// magic-div /196 (exact for row<50176), fast_tanh, shfl-reduce, atomicAdd.
// ===========================================================================
#define SBAR()                          \
  __builtin_amdgcn_sched_barrier(0);    \
  __builtin_amdgcn_s_barrier();         \
  __builtin_amdgcn_sched_barrier(0);

__global__ __launch_bounds__(512) void gemm_scores_8ph(
    const unsigned short* __restrict__ A, const unsigned short* __restrict__ B,
    const float* __restrict__ qv, const float* __restrict__ bkv,
    const float* __restrict__ vvec, float* __restrict__ scores)
{
  constexpr int KSH = 2048;  // K in shorts
  constexpr int NT  = 32;    // K-tiles of 64
  __shared__ __align__(16) unsigned short lds[2 * 4 * 8192];  // 128 KiB

  const int tid  = threadIdx.x;
  const int w    = tid >> 6;   // wave 0..7
  const int lane = tid & 63;
  const int qd = lane >> 4, lm = lane & 15;
  const int wm = w >> 2;       // 0..1
  const int wn = w & 3;        // 0..3

  const int n0 = blockIdx.x * 256;
  const int m0 = blockIdx.y * 256;

  // staging source offsets (shorts): row (w*16+i*8+(l>>3)), chunk (l&7)^(l>>3)
  const int off0 = (w * 16 + 0 + (lane >> 3)) * KSH + ((lane & 7) ^ (lane >> 3)) * 8;
  const int off1 = (w * 16 + 8 + (lane >> 3)) * KSH + ((lane & 7) ^ (lane >> 3)) * 8;

  const unsigned short* srcu[4] = {
      A + (size_t)m0 * KSH, A + (size_t)(m0 + 128) * KSH,
      B + (size_t)n0 * KSH, B + (size_t)(n0 + 128) * KSH};

#define STAGE(u, tt)                                                          \
  {                                                                           \
    const unsigned short* s_ = srcu[u] + (tt) * 64;                           \
    unsigned short* d_ = &lds[(((tt) & 1) * 4 + (u)) * 8192 + w * 1024];      \
    gload_lds16(s_ + off0, d_);                                               \
    gload_lds16(s_ + off1, d_ + 512);                                         \
  }

  const int fswz = lm & 7;
#define READ_A(mh)                                                            \
  _Pragma("unroll") for (int mf = 0; mf < 4; ++mf)                            \
  _Pragma("unroll") for (int kk = 0; kk < 2; ++kk)                            \
      af[mf][kk] = *(const bf16x8*)&Ab_[((mh)*64 + mf * 16 + lm) * 64 +       \
                                        ((kk * 4 + qd) ^ fswz) * 8];

#define READ_B(nh, dst)                                                       \
  _Pragma("unroll") for (int nf = 0; nf < 2; ++nf)                            \
  _Pragma("unroll") for (int kk = 0; kk < 2; ++kk)                            \
      dst[nf][kk] = *(const bf16x8*)&Bb_[(bro + (nh)*32 + nf * 16 + lm) * 64 +\
                                         ((kk * 4 + qd) ^ fswz) * 8];

#define QUAD(mh, nh, bsrc)                                                    \
  _Pragma("unroll") for (int mf = 0; mf < 4; ++mf)                            \
  _Pragma("unroll") for (int nf = 0; nf < 2; ++nf)                            \
  _Pragma("unroll") for (int kk = 0; kk < 2; ++kk)                            \
      acc[(mh)*4 + mf][(nh)*2 + nf] = __builtin_amdgcn_mfma_f32_16x16x32_bf16(\
          af[mf][kk], bsrc[nf][kk], acc[(mh)*4 + mf][(nh)*2 + nf], 0, 0, 0);

  floatx4 acc[8][4];
#pragma unroll
  for (int i = 0; i < 8; ++i)
#pragma unroll
    for (int j = 0; j < 4; ++j)
#pragma unroll
      for (int r = 0; r < 4; ++r) acc[i][j][r] = 0.0f;

  // prologue: tile0 all 4 units, tile1 B0,B1,A0 (A1(1) staged at iter0 ph0)
  STAGE(0, 0) STAGE(1, 0) STAGE(2, 0) STAGE(3, 0)
  STAGE(2, 1) STAGE(3, 1) STAGE(0, 1)
  asm volatile("s_waitcnt vmcnt(6)" ::: "memory");
  SBAR();

  const int bro = (wn & 1) * 64;
  bf16x8 af[4][2], b0[2][2], b1[2][2];

#pragma unroll 2
  for (int t = 0; t < NT; ++t) {
    const unsigned short* Ab_ = &lds[(t & 1) * 32768 + wm * 8192];
    const unsigned short* Bb_ = &lds[(t & 1) * 32768 + (2 + (wn >> 1)) * 8192];
    // ---- ph0: Q(0,0)
    READ_A(0)
    READ_B(0, b0)
    if (t + 1 < NT) STAGE(1, t + 1)
    SBAR();
    __builtin_amdgcn_s_setprio(1);
    QUAD(0, 0, b0)
    __builtin_amdgcn_s_setprio(0);
    SBAR();
    // ---- ph1: Q(0,1)
    READ_B(1, b1)
    SBAR();
    __builtin_amdgcn_s_setprio(1);
    QUAD(0, 1, b1)
    __builtin_amdgcn_s_setprio(0);
    SBAR();
    // ---- ph2: Q(1,0)
    READ_A(1)
    if (t + 2 < NT) STAGE(2, t + 2)
    SBAR();
    __builtin_amdgcn_s_setprio(1);
    QUAD(1, 0, b0)
    __builtin_amdgcn_s_setprio(0);
    SBAR();
    // ---- ph3: Q(1,1)
    if (t + 2 < NT) { STAGE(3, t + 2) STAGE(0, t + 2) }
    SBAR();
    __builtin_amdgcn_s_setprio(1);
    QUAD(1, 1, b1)
    __builtin_amdgcn_s_setprio(0);
    if (t + 2 < NT) {
      asm volatile("s_waitcnt vmcnt(6)" ::: "memory");
    } else if (t + 1 < NT) {
      asm volatile("s_waitcnt vmcnt(0)" ::: "memory");
    }
    SBAR();
  }

  // ---- epilogue: scores
  float vj[4], bkj[4];
  int gcj[4];
#pragma unroll
  for (int nf = 0; nf < 4; ++nf) {
    gcj[nf] = n0 + wn * 64 + nf * 16 + lm;
    vj[nf]  = vvec[gcj[nf]];
    bkj[nf] = bkv[gcj[nf]];
  }
#pragma unroll
  for (int mf = 0; mf < 8; ++mf) {
#pragma unroll
    for (int r = 0; r < 4; ++r) {
      const int grow = m0 + wm * 128 + mf * 16 + qd * 4 + r;
      const int brow = (int)((unsigned)(grow * 85599u) >> 24);  // /196 exact
      const float* qrow = qv + (size_t)brow * 1024;
      float s = 0.0f;
#pragma unroll
      for (int nf = 0; nf < 4; ++nf)
        s += fast_tanh(qrow[gcj[nf]] + bkj[nf] + acc[mf][nf][r]) * vj[nf];
      s += __shfl_xor(s, 1, 64);
      s += __shfl_xor(s, 2, 64);
      s += __shfl_xor(s, 4, 64);
      s += __shfl_xor(s, 8, 64);
      if (lm == 0) atomicAdd(&scores[grow], s);
    }
  }
#undef STAGE
#undef READ_A
#undef READ_B
#undef QUAD
}

// ---------------------------------------------------------------------------
// C[M x N] = A[M x K] @ Bt[N x K]^T (+epilogue), bf16 MFMA 16x16x32.
// BM=BN=128, BK=32, 256 thr = 4 waves 2x2, wave = 64x64 (4x4 MFMA tiles).
// (see prior rounds; serves all non-scores GEMMs)
// ---------------------------------------------------------------------------
template <int EPI, bool ABF16, bool XSWZ>
__global__ __launch_bounds__(256) void gemm_bt(
    const float* __restrict__ Af, const unsigned short* __restrict__ Ab, int lda,
    const unsigned short* __restrict__ Bt, int ldb, int Kc,
    float* __restrict__ C, int ldc, int coloff, const float* __restrict__ bias,
    const float* __restrict__ qv, const float* __restrict__ bkv,
    const float* __restrict__ vvec, float* __restrict__ scores, int Lrows, int Hdim)
{
  __shared__ __align__(16) unsigned short As[128 * 32];
  __shared__ __align__(16) unsigned short Bs[128 * 32];

  const int tid  = threadIdx.x;
  const int wave = tid >> 6;
  const int lane = tid & 63;
  const int qd   = lane >> 4;
  const int lm   = lane & 15;
  const int wr   = wave >> 1;
  const int wc   = wave & 1;

  int bx = blockIdx.x, by = blockIdx.y;
  if (XSWZ) {
    const int id = by * 8 + bx;
    const int c = id >> 6, r = id & 63;
    by = c * 8 + (r & 7);
    bx = r >> 3;
  }
  const long n0 = (long)bx * 128;
  const long m0 = (long)by * 128;
  const long k0base = (long)blockIdx.z * Kc;

  floatx4 acc[4][4];
#pragma unroll
  for (int i = 0; i < 4; ++i)
#pragma unroll
    for (int j = 0; j < 4; ++j)
#pragma unroll
      for (int r = 0; r < 4; ++r) acc[i][j][r] = 0.0f;

  const int srow = lane >> 2;
  const int scg  = ((lane & 3) ^ ((lane >> 2) & 3) ^ (lane >> 4)) * 8;
  const int arow = tid >> 1;
  const int q0   = (tid & 1) * 2;
  const int sA   = ((arow & 3) ^ ((arow >> 2) & 3));
  const int fsw  = (qd ^ ((lm ^ (lm >> 2)) & 3)) * 8;

  const int nIter = Kc >> 5;
  for (int it = 0; it < nIter; ++it) {
    const long k0 = k0base + ((long)it << 5);
    {
      const unsigned short* bsrc = Bt + n0 * (size_t)ldb + k0;
#pragma unroll
      for (int q2 = 0; q2 < 2; ++q2) {
        const int rb = wave * 32 + q2 * 16;
        gload_lds16(bsrc + (size_t)(rb + srow) * ldb + scg, &Bs[rb * 32]);
      }
    }
    if (ABF16) {
      const unsigned short* asrc = Ab + m0 * (size_t)lda + k0;
#pragma unroll
      for (int q2 = 0; q2 < 2; ++q2) {
        const int rb = wave * 32 + q2 * 16;
        gload_lds16(asrc + (size_t)(rb + srow) * lda + scg, &As[rb * 32]);
      }
    } else {
      const float* ap = Af + (m0 + arow) * (size_t)lda + k0 + q0 * 8;
      floatx4 f0 = *(const floatx4*)(ap + 0);
      floatx4 f1 = *(const floatx4*)(ap + 4);
      floatx4 f2 = *(const floatx4*)(ap + 8);
      floatx4 f3 = *(const floatx4*)(ap + 12);
      ushortx8 u0, u1;
#pragma unroll
      for (int e = 0; e < 4; ++e) {
        u0[e]     = f2bf(f0[e]);
        u0[e + 4] = f2bf(f1[e]);
        u1[e]     = f2bf(f2[e]);
        u1[e + 4] = f2bf(f3[e]);
      }
      *(ushortx8*)&As[arow * 32 + (q0 ^ sA) * 8]       = u0;
      *(ushortx8*)&As[arow * 32 + ((q0 + 1) ^ sA) * 8] = u1;
    }
    __syncthreads();

    bf16x8 af[4], bfr[4];
#pragma unroll
    for (int i = 0; i < 4; ++i) {
      const int m = wr * 64 + i * 16 + lm;
      af[i] = *(const bf16x8*)&As[m * 32 + fsw];
    }
#pragma unroll
    for (int j = 0; j < 4; ++j) {
      const int n = wc * 64 + j * 16 + lm;
      bfr[j] = *(const bf16x8*)&Bs[n * 32 + fsw];
    }
#pragma unroll
    for (int i = 0; i < 4; ++i)
#pragma unroll
      for (int j = 0; j < 4; ++j)
        acc[i][j] = __builtin_amdgcn_mfma_f32_16x16x32_bf16(af[i], bfr[j], acc[i][j], 0, 0, 0);
    __syncthreads();
  }

  if (EPI == 0) {
#pragma unroll
    for (int j = 0; j < 4; ++j) {
      const long gc = n0 + wc * 64 + j * 16 + lm;
      const float bj = bias[gc];
#pragma unroll
      for (int i = 0; i < 4; ++i) {
        const long gr0 = m0 + wr * 64 + i * 16 + qd * 4;
#pragma unroll
        for (int r = 0; r < 4; ++r)
          C[(gr0 + r) * (size_t)ldc + coloff + gc] = acc[i][j][r] + bj;
      }
    }
  } else if (EPI == 2) {
#pragma unroll
    for (int j = 0; j < 4; ++j) {
      const long gc = n0 + wc * 64 + j * 16 + lm;
      const float bj = (blockIdx.z == 0) ? bias[gc] : 0.0f;
#pragma unroll
      for (int i = 0; i < 4; ++i) {
        const long gr0 = m0 + wr * 64 + i * 16 + qd * 4;
#pragma unroll
        for (int r = 0; r < 4; ++r)
          atomicAdd(&C[(gr0 + r) * (size_t)ldc + coloff + gc], acc[i][j][r] + bj);
      }
    }
  } else {
    float vj[4], bkj[4];
    int gcj[4];
#pragma unroll
    for (int j = 0; j < 4; ++j) {
      gcj[j] = (int)(n0 + wc * 64 + j * 16 + lm);
      vj[j]  = vvec[gcj[j]];
      bkj[j] = bkv[gcj[j]];
    }
    const int m0i = (int)m0;
#pragma unroll
    for (int i = 0; i < 4; ++i) {
#pragma unroll
      for (int r = 0; r < 4; ++r) {
        const int grow = m0i + wr * 64 + i * 16 + qd * 4 + r;
        int brow;
        if (Lrows == 196) brow = (int)((unsigned)(grow * 85599u) >> 24);
        else              brow = grow / Lrows;
        const float* qrow = qv + (size_t)brow * Hdim;
        float s = 0.0f;
#pragma unroll
        for (int j = 0; j < 4; ++j)
          s += fast_tanh(qrow[gcj[j]] + bkj[j] + acc[i][j][r]) * vj[j];
        s += __shfl_xor(s, 1, 64);
        s += __shfl_xor(s, 2, 64);
        s += __shfl_xor(s, 4, 64);
        s += __shfl_xor(s, 8, 64);
        if (lm == 0) atomicAdd(&scores[grow], s);
      }
    }
  }
}

// --------------------------- prep kernels ----------------------------------
__global__ void transpose_f32_bf16(const float* __restrict__ in,
                                   unsigned short* __restrict__ out, int R, int C) {
  __shared__ float tile[32][33];
  const int c0 = blockIdx.x * 32, r0 = blockIdx.y * 32;
  const int tx = threadIdx.x, ty = threadIdx.y;  // (32,8)
#pragma unroll
  for (int yy = 0; yy < 4; ++yy)
    tile[ty + 8 * yy][tx] = in[(size_t)(r0 + ty + 8 * yy) * C + c0 + tx];
  __syncthreads();
#pragma unroll
  for (int yy = 0; yy < 4; ++yy)
    out[(size_t)(c0 + ty + 8 * yy) * R + r0 + tx] = f2bf(tile[tx][ty + 8 * yy]);
}

__global__ void convert_bf16(const float* __restrict__ in,
                             unsigned short* __restrict__ out, int n4) {
  const int idx = blockIdx.x * blockDim.x + threadIdx.x;
  if (idx < n4) {
    floatx4 f = *(const floatx4*)(in + 4 * (size_t)idx);
    ushortx4 u;
#pragma unroll
    for (int e = 0; e < 4; ++e) u[e] = f2bf(f[e]);
    *(ushortx4*)(out + 4 * (size_t)idx) = u;
  }
}

__global__ void gather_emb(const int* __restrict__ inputs, const float* __restrict__ emb,
                           float* __restrict__ rnn_in, int E, int ldr) {
  const int b = blockIdx.x, t = threadIdx.x;
  const int row = inputs[b];
  for (int e = t; e < E; e += 256)
    rnn_in[(size_t)b * ldr + e] = emb[(size_t)row * E + e];
}

// ----------------------------- softmax over L ------------------------------
__global__ __launch_bounds__(256) void softmax_w(
    const float* __restrict__ scores, const float* __restrict__ bv,
    float* __restrict__ weights, int L)
{
  __shared__ float red[8];
  const int b = blockIdx.x, t = threadIdx.x;
  const int wave = t >> 6;
  float s = (t < L) ? scores[(size_t)b * L + t] + bv[0] : -3.4e38f;
  float m = s;
  for (int o = 32; o > 0; o >>= 1) m = fmaxf(m, __shfl_xor(m, o, 64));
  if ((t & 63) == 0) red[wave] = m;
  __syncthreads();
  m = fmaxf(fmaxf(red[0], red[1]), fmaxf(red[2], red[3]));
  float e = (t < L) ? __expf(s - m) : 0.0f;
  float sum = e;
  for (int o = 32; o > 0; o >>= 1) sum += __shfl_xor(sum, o, 64);
  if ((t & 63) == 0) red[4 + wave] = sum;
  __syncthreads();
  sum = red[4] + red[5] + red[6] + red[7];
  if (t < L) weights[(size_t)b * L + t] = e / sum;
}

// ------------------- context[b,k] = sum_l w[b,l]*keys[b,l,k] ---------------
template <bool KB16>
__global__ __launch_bounds__(256) void context_k(
    const float* __restrict__ weights, const unsigned short* __restrict__ keys16,
    const float* __restrict__ keysf, float* __restrict__ context, int L, int K)
{
  __shared__ float w[256];
  const int b = blockIdx.x, t = threadIdx.x;
  if (t < L) w[t] = weights[(size_t)b * L + t];
  __syncthreads();
  const int col0 = blockIdx.y * 512 + t * 2;
  float a0 = 0.0f, a1 = 0.0f;
  if (KB16) {
    const unsigned short* kp = keys16 + (size_t)b * L * K + col0;
#pragma unroll 4
    for (int l = 0; l < L; ++l) {
      const unsigned int u = *(const unsigned int*)(kp + (size_t)l * K);
      a0 += w[l] * bf2f((unsigned short)(u & 0xffff));
      a1 += w[l] * bf2f((unsigned short)(u >> 16));
    }
  } else {
    const float* kp = keysf + (size_t)b * L * K + col0;
#pragma unroll 4
    for (int l = 0; l < L; ++l) {
      a0 += w[l] * kp[(size_t)l * K];
      a1 += w[l] * kp[(size_t)l * K + 1];
    }
  }
  context[(size_t)b * K + col0]     = a0;
  context[(size_t)b * K + col0 + 1] = a1;
}

// ------------------------------- GRU cell ----------------------------------
__global__ void gru_kernel(const float* __restrict__ gi, const float* __restrict__ gh,
                           const float* __restrict__ hidden, float* __restrict__ hnew, int H) {
  const int idx = blockIdx.x * blockDim.x + threadIdx.x;  // B*H
  const int b = idx / H, h = idx % H;
  const size_t base = (size_t)b * 3 * H;
  const float ir = gi[base + h], iz = gi[base + H + h], inn = gi[base + 2 * H + h];
  const float hr = gh[base + h], hz = gh[base + H + h], hn = gh[base + 2 * H + h];
  const float r = 1.0f / (1.0f + __expf(-(ir + hr)));
  const float z = 1.0f / (1.0f + __expf(-(iz + hz)));
  const float n = tanhf(inn + r * hn);
  const float hv = hidden[(size_t)b * H + h];
  hnew[(size_t)b * H + h] = (1.0f - z) * n + z * hv;
}

// ---------------------------------------------------------------------------
extern "C" void kernel_launch(void* const* d_in, const int* in_sizes, int n_in,
                              void* d_out, int out_size, void* d_ws, size_t ws_size,
                              hipStream_t stream) {
  constexpr int V = 32000, E = 512, H = 1024, KD = 2048, L = 196, B = 256;
  constexpr int G3 = 3 * H;   // 3072
  constexpr int EH = E + H;   // 1536

  const int*   inputs = (const int*)d_in[0];
  const float* hidden = (const float*)d_in[1];
  const float* keys   = (const float*)d_in[2];
  const float* emb    = (const float*)d_in[3];
  const float* Wq     = (const float*)d_in[4];
  const float* bq     = (const float*)d_in[5];
  const float* Wk     = (const float*)d_in[6];
  const float* bk     = (const float*)d_in[7];
  const float* vvec   = (const float*)d_in[8];
  const float* bv     = (const float*)d_in[9];
  const float* fc0_W  = (const float*)d_in[10];
  const float* fc0_b  = (const float*)d_in[11];
  const float* W_ih   = (const float*)d_in[12];
  const float* W_hh   = (const float*)d_in[13];
  const float* b_ih   = (const float*)d_in[14];
  const float* b_hh   = (const float*)d_in[15];
  const float* fc1_W  = (const float*)d_in[16];
  const float* fc1_b  = (const float*)d_in[17];

  float* logits  = (float*)d_out;
  float* hnew    = logits + (size_t)B * V;
  float* weights = hnew + (size_t)B * H;

  char* ws = (char*)d_ws;
  size_t off = 0;
  auto bump = [&off](size_t bytes) {
    size_t p = off;
    off += (bytes + 255) & ~(size_t)255;
    return p;
  };
  unsigned short* WqT   = (unsigned short*)(ws + bump((size_t)H * H * 2));
  unsigned short* WkT   = (unsigned short*)(ws + bump((size_t)H * KD * 2));
  unsigned short* fc0T  = (unsigned short*)(ws + bump((size_t)H * KD * 2));
  unsigned short* fc1T  = (unsigned short*)(ws + bump((size_t)V * H * 2));
  unsigned short* Wih16 = (unsigned short*)(ws + bump((size_t)G3 * EH * 2));
  unsigned short* Whh16 = (unsigned short*)(ws + bump((size_t)G3 * H * 2));
  float* qbuf    = (float*)(ws + bump((size_t)B * H * 4));
  float* scoresb = (float*)(ws + bump((size_t)B * L * 4));
  float* context = (float*)(ws + bump((size_t)B * KD * 4));
  float* rnn_in  = (float*)(ws + bump((size_t)B * EH * 4));
  float* gi      = (float*)(ws + bump((size_t)B * G3 * 4));
  float* gh      = (float*)(ws + bump((size_t)B * G3 * 4));
  unsigned short* keys16 = (unsigned short*)(ws + bump((size_t)B * L * KD * 2));
  const bool useK16 = (off <= ws_size);  // constant across calls -> graph-safe

  // split-K targets must start from zero (ws is re-poisoned before each call)
  hipMemsetAsync(scoresb, 0, (size_t)B * L * 4, stream);
  hipMemsetAsync(qbuf, 0, (size_t)B * H * 4, stream);
  hipMemsetAsync(rnn_in, 0, (size_t)B * EH * 4, stream);
  hipMemsetAsync(gi, 0, (size_t)B * G3 * 4, stream);
  hipMemsetAsync(gh, 0, (size_t)B * G3 * 4, stream);

  const dim3 tb(32, 8);
  transpose_f32_bf16<<<dim3(H / 32, H / 32), tb, 0, stream>>>(Wq, WqT, H, H);
  transpose_f32_bf16<<<dim3(H / 32, KD / 32), tb, 0, stream>>>(Wk, WkT, KD, H);
  transpose_f32_bf16<<<dim3(H / 32, KD / 32), tb, 0, stream>>>(fc0_W, fc0T, KD, H);
  transpose_f32_bf16<<<dim3(V / 32, H / 32), tb, 0, stream>>>(fc1_W, fc1T, H, V);
  convert_bf16<<<(G3 * EH / 4 + 255) / 256, 256, 0, stream>>>(W_ih, Wih16, G3 * EH / 4);
  convert_bf16<<<(G3 * H / 4 + 255) / 256, 256, 0, stream>>>(W_hh, Whh16, G3 * H / 4);
  if (useK16) {
    const int n4 = B * L * KD / 4;
    convert_bf16<<<(n4 + 255) / 256, 256, 0, stream>>>(keys, keys16, n4);
  }

  gather_emb<<<B, 256, 0, stream>>>(inputs, emb, rnn_in, E, EH);

  // q = hidden @ Wq + bq   (split-K x4 -> 64 blocks instead of 16)
  gemm_bt<2, false, false><<<dim3(H / 128, B / 128, 4), 256, 0, stream>>>(
      hidden, nullptr, H, WqT, H, H / 4, qbuf, H, 0, bq,
      nullptr, nullptr, nullptr, nullptr, 0, 0);

  // scores[b*L+l] = tanh(q[b]+bk+keys[b,l]@Wk) . v   (the 210 GFLOP GEMM)
  if (useK16)
    gemm_scores_8ph<<<dim3((H) / 256, (B * L) / 256, 1), 512, 0, stream>>>(
        keys16, WkT, qbuf, bk, vvec, scoresb);
  else
    gemm_bt<1, false, true><<<dim3(H / 128, (B * L) / 128, 1), 256, 0, stream>>>(
        keys, nullptr, KD, WkT, KD, KD, nullptr, 0, 0, nullptr,
        qbuf, bk, vvec, scoresb, L, H);

  softmax_w<<<B, 256, 0, stream>>>(scoresb, bv, weights, L);

  if (useK16)
    context_k<true><<<dim3(B, KD / 512), 256, 0, stream>>>(weights, keys16, nullptr,
                                                           context, L, KD);
  else
    context_k<false><<<dim3(B, KD / 512), 256, 0, stream>>>(weights, nullptr, keys,
                                                            context, L, KD);

  // rnn_in[:, E:] = context @ fc0_W + fc0_b   (split-K x4)
  gemm_bt<2, false, false><<<dim3(H / 128, B / 128, 4), 256, 0, stream>>>(
      context, nullptr, KD, fc0T, KD, KD / 4, rnn_in, EH, E, fc0_b,
      nullptr, nullptr, nullptr, nullptr, 0, 0);

  // gi = rnn_in @ W_ih^T + b_ih   (split-K x4)
  gemm_bt<2, false, false><<<dim3(G3 / 128, B / 128, 4), 256, 0, stream>>>(
      rnn_in, nullptr, EH, Wih16, EH, EH / 4, gi, G3, 0, b_ih,
      nullptr, nullptr, nullptr, nullptr, 0, 0);

  // gh = hidden @ W_hh^T + b_hh   (split-K x4)
  gemm_bt<2, false, false><<<dim3(G3 / 128, B / 128, 4), 256, 0, stream>>>(
      hidden, nullptr, H, Whh16, H, H / 4, gh, G3, 0, b_hh,
      nullptr, nullptr, nullptr, nullptr, 0, 0);

  gru_kernel<<<(B * H) / 256, 256, 0, stream>>>(gi, gh, hidden, hnew, H);

  // logits = h_new @ fc1_W + fc1_b  (500 blocks, no split needed)
  gemm_bt<0, false, false><<<dim3(V / 128, B / 128, 1), 256, 0, stream>>>(
      hnew, nullptr, H, fc1T, H, H, logits, V, 0, fc1_b,
      nullptr, nullptr, nullptr, nullptr, 0, 0);
}

// Round 4
// 1202.393 us; speedup vs baseline: 1.0870x; 1.0015x over previous
//
#include <hip/hip_runtime.h>
#include <cstdint>

#define DEVINL __device__ __forceinline__

typedef __attribute__((ext_vector_type(4))) float floatx4;
typedef __attribute__((ext_vector_type(8))) __bf16 bf16x8;
typedef __attribute__((ext_vector_type(8))) unsigned short ushortx8;
typedef __attribute__((ext_vector_type(4))) unsigned short ushortx4;

DEVINL unsigned short f2bf(float x) {  // RNE fp32 -> bf16 (finite inputs)
  unsigned int u = __float_as_uint(x);
  u += 0x7fffu + ((u >> 16) & 1u);
  return (unsigned short)(u >> 16);
}
DEVINL float bf2f(unsigned short u) { return __uint_as_float(((unsigned int)u) << 16); }

DEVINL float fast_tanh(float x) {  // branch-free: 1 - 2/(e^{2x}+1); exact at +-inf
  return 1.0f - 2.0f / (__expf(2.0f * x) + 1.0f);
}

DEVINL void gload_lds16(const void* g, void* l) {
  __builtin_amdgcn_global_load_lds(
      (const __attribute__((address_space(1))) void*)g,
      (__attribute__((address_space(3))) void*)l, 16, 0, 0);
}

// ===========================================================================
// 8-phase 256x256 BK=64 scores GEMM (T2+T3+T4+T5 per catalog).
// A = keys16 [M=50176][K=2048] bf16, B = WkT [N=1024][K=2048] bf16.
// 512 thr = 8 waves (2M x 4N); per-wave output 128x64 = acc[8][4] f32x4.
// LDS 128 KiB: 2 buffers x 4 units (A0,A1,B0,B1) x [128 rows][64 cols] bf16.
// Swizzle: 16B chunk slot s of row r holds data chunk s ^ (r&7) -> ds_read
// <=2-way bank conflict (free); gload_lds dst is lane-linear, src pre-swizzled
// (chunk = (l&7)^(l>>3), lane-only constant).
// R4: bijective XCD swizzle (784%8==0): hw id h -> logical (h&7)*98 + h/8,
// so each XCD owns 98 contiguous logical tiles; the 4 bx blocks sharing an
// A-panel run concurrently on ONE XCD -> A fetched once per panel (R3 showed
// FETCH 418 MB ~= 2x A, cold-HBM latency exposed at the counted vmcnt wait).
// Phases per K-tile t:
//   ph0: read A(mh0,8xb128)+B(nh0,4); stage A1(t+1); Q(0,0)
//   ph1: read B(nh1,4);               Q(0,1)
//   ph2: read A(mh1,8); stage B0(t+2); Q(1,0)
//   ph3: stage B1(t+2)+A0(t+2);        Q(1,1); s_waitcnt vmcnt(6); barrier
// Steady state: 6 loads in flight across the K-tile boundary; wait is
// counted, never a drain.  WAR safety verified per-region (see R2 notes).
// Epilogue: scores[row] += sum_n tanh(q[row/196][n]+bk[n]+acc)*v[n],
// magic-div /196 (exact for row<50176), fast_tanh, shfl-reduce, atomicAdd.
// ===========================================================================
#define SBAR()                          \
  __builtin_amdgcn_sched_barrier(0);    \
  __builtin_amdgcn_s_barrier();         \
  __builtin_amdgcn_sched_barrier(0);

__global__ __launch_bounds__(512) void gemm_scores_8ph(
    const unsigned short* __restrict__ A, const unsigned short* __restrict__ B,
    const float* __restrict__ qv, const float* __restrict__ bkv,
    const float* __restrict__ vvec, float* __restrict__ scores)
{
  constexpr int KSH = 2048;  // K in shorts
  constexpr int NT  = 32;    // K-tiles of 64
  __shared__ __align__(16) unsigned short lds[2 * 4 * 8192];  // 128 KiB

  const int tid  = threadIdx.x;
  const int w    = tid >> 6;   // wave 0..7
  const int lane = tid & 63;
  const int qd = lane >> 4, lm = lane & 15;
  const int wm = w >> 2;       // 0..1
  const int wn = w & 3;        // 0..3

  // XCD-chunked bijective remap: 784 blocks, 8 XCDs, 98 logical tiles each.
  // hw id h (round-robin h%8 -> XCD) -> logical = (h&7)*98 + h/8.
  const int h = blockIdx.x;
  const int logical = (h & 7) * 98 + (h >> 3);
  const int n0 = (logical & 3) * 256;   // bx in [0,4)
  const int m0 = (logical >> 2) * 256;  // by in [0,196)

  // staging source offsets (shorts): row (w*16+i*8+(l>>3)), chunk (l&7)^(l>>3)
  const int off0 = (w * 16 + 0 + (lane >> 3)) * KSH + ((lane & 7) ^ (lane >> 3)) * 8;
  const int off1 = (w * 16 + 8 + (lane >> 3)) * KSH + ((lane & 7) ^ (lane >> 3)) * 8;

  const unsigned short* srcu[4] = {
      A + (size_t)m0 * KSH, A + (size_t)(m0 + 128) * KSH,
      B + (size_t)n0 * KSH, B + (size_t)(n0 + 128) * KSH};

#define STAGE(u, tt)                                                          \
  {                                                                           \
    const unsigned short* s_ = srcu[u] + (tt) * 64;                           \
    unsigned short* d_ = &lds[(((tt) & 1) * 4 + (u)) * 8192 + w * 1024];      \
    gload_lds16(s_ + off0, d_);                                               \
    gload_lds16(s_ + off1, d_ + 512);                                         \
  }

  const int fswz = lm & 7;
#define READ_A(mh)                                                            \
  _Pragma("unroll") for (int mf = 0; mf < 4; ++mf)                            \
  _Pragma("unroll") for (int kk = 0; kk < 2; ++kk)                            \
      af[mf][kk] = *(const bf16x8*)&Ab_[((mh)*64 + mf * 16 + lm) * 64 +       \
                                        ((kk * 4 + qd) ^ fswz) * 8];

#define READ_B(nh, dst)                                                       \
  _Pragma("unroll") for (int nf = 0; nf < 2; ++nf)                            \
  _Pragma("unroll") for (int kk = 0; kk < 2; ++kk)                            \
      dst[nf][kk] = *(const bf16x8*)&Bb_[(bro + (nh)*32 + nf * 16 + lm) * 64 +\
                                         ((kk * 4 + qd) ^ fswz) * 8];

#define QUAD(mh, nh, bsrc)                                                    \
  _Pragma("unroll") for (int mf = 0; mf < 4; ++mf)                            \
  _Pragma("unroll") for (int nf = 0; nf < 2; ++nf)                            \
  _Pragma("unroll") for (int kk = 0; kk < 2; ++kk)                            \
      acc[(mh)*4 + mf][(nh)*2 + nf] = __builtin_amdgcn_mfma_f32_16x16x32_bf16(\
          af[mf][kk], bsrc[nf][kk], acc[(mh)*4 + mf][(nh)*2 + nf], 0, 0, 0);

  floatx4 acc[8][4];
#pragma unroll
  for (int i = 0; i < 8; ++i)
#pragma unroll
    for (int j = 0; j < 4; ++j)
#pragma unroll
      for (int r = 0; r < 4; ++r) acc[i][j][r] = 0.0f;

  // prologue: tile0 all 4 units, tile1 B0,B1,A0 (A1(1) staged at iter0 ph0)
  STAGE(0, 0) STAGE(1, 0) STAGE(2, 0) STAGE(3, 0)
  STAGE(2, 1) STAGE(3, 1) STAGE(0, 1)
  asm volatile("s_waitcnt vmcnt(6)" ::: "memory");
  SBAR();

  const int bro = (wn & 1) * 64;
  bf16x8 af[4][2], b0[2][2], b1[2][2];

#pragma unroll 2
  for (int t = 0; t < NT; ++t) {
    const unsigned short* Ab_ = &lds[(t & 1) * 32768 + wm * 8192];
    const unsigned short* Bb_ = &lds[(t & 1) * 32768 + (2 + (wn >> 1)) * 8192];
    // ---- ph0: Q(0,0)
    READ_A(0)
    READ_B(0, b0)
    if (t + 1 < NT) STAGE(1, t + 1)
    SBAR();
    __builtin_amdgcn_s_setprio(1);
    QUAD(0, 0, b0)
    __builtin_amdgcn_s_setprio(0);
    SBAR();
    // ---- ph1: Q(0,1)
    READ_B(1, b1)
    SBAR();
    __builtin_amdgcn_s_setprio(1);
    QUAD(0, 1, b1)
    __builtin_amdgcn_s_setprio(0);
    SBAR();
    // ---- ph2: Q(1,0)
    READ_A(1)
    if (t + 2 < NT) STAGE(2, t + 2)
    SBAR();
    __builtin_amdgcn_s_setprio(1);
    QUAD(1, 0, b0)
    __builtin_amdgcn_s_setprio(0);
    SBAR();
    // ---- ph3: Q(1,1)
    if (t + 2 < NT) { STAGE(3, t + 2) STAGE(0, t + 2) }
    SBAR();
    __builtin_amdgcn_s_setprio(1);
    QUAD(1, 1, b1)
    __builtin_amdgcn_s_setprio(0);
    if (t + 2 < NT) {
      asm volatile("s_waitcnt vmcnt(6)" ::: "memory");
    } else if (t + 1 < NT) {
      asm volatile("s_waitcnt vmcnt(0)" ::: "memory");
    }
    SBAR();
  }

  // ---- epilogue: scores
  float vj[4], bkj[4];
  int gcj[4];
#pragma unroll
  for (int nf = 0; nf < 4; ++nf) {
    gcj[nf] = n0 + wn * 64 + nf * 16 + lm;
    vj[nf]  = vvec[gcj[nf]];
    bkj[nf] = bkv[gcj[nf]];
  }
#pragma unroll
  for (int mf = 0; mf < 8; ++mf) {
#pragma unroll
    for (int r = 0; r < 4; ++r) {
      const int grow = m0 + wm * 128 + mf * 16 + qd * 4 + r;
      const int brow = (int)((unsigned)(grow * 85599u) >> 24);  // /196 exact
      const float* qrow = qv + (size_t)brow * 1024;
      float s = 0.0f;
#pragma unroll
      for (int nf = 0; nf < 4; ++nf)
        s += fast_tanh(qrow[gcj[nf]] + bkj[nf] + acc[mf][nf][r]) * vj[nf];
      s += __shfl_xor(s, 1, 64);
      s += __shfl_xor(s, 2, 64);
      s += __shfl_xor(s, 4, 64);
      s += __shfl_xor(s, 8, 64);
      if (lm == 0) atomicAdd(&scores[grow], s);
    }
  }
#undef STAGE
#undef READ_A
#undef READ_B
#undef QUAD
}

// ---------------------------------------------------------------------------
// C[M x N] = A[M x K] @ Bt[N x K]^T (+epilogue), bf16 MFMA 16x16x32.
// BM=BN=128, BK=32, 256 thr = 4 waves 2x2, wave = 64x64 (4x4 MFMA tiles).
// (see prior rounds; serves all non-scores GEMMs)
// ---------------------------------------------------------------------------
template <int EPI, bool ABF16, bool XSWZ>
__global__ __launch_bounds__(256) void gemm_bt(
    const float* __restrict__ Af, const unsigned short* __restrict__ Ab, int lda,
    const unsigned short* __restrict__ Bt, int ldb, int Kc,
    float* __restrict__ C, int ldc, int coloff, const float* __restrict__ bias,
    const float* __restrict__ qv, const float* __restrict__ bkv,
    const float* __restrict__ vvec, float* __restrict__ scores, int Lrows, int Hdim)
{
  __shared__ __align__(16) unsigned short As[128 * 32];
  __shared__ __align__(16) unsigned short Bs[128 * 32];

  const int tid  = threadIdx.x;
  const int wave = tid >> 6;
  const int lane = tid & 63;
  const int qd   = lane >> 4;
  const int lm   = lane & 15;
  const int wr   = wave >> 1;
  const int wc   = wave & 1;

  int bx = blockIdx.x, by = blockIdx.y;
  if (XSWZ) {
    const int id = by * 8 + bx;
    const int c = id >> 6, r = id & 63;
    by = c * 8 + (r & 7);
    bx = r >> 3;
  }
  const long n0 = (long)bx * 128;
  const long m0 = (long)by * 128;
  const long k0base = (long)blockIdx.z * Kc;

  floatx4 acc[4][4];
#pragma unroll
  for (int i = 0; i < 4; ++i)
#pragma unroll
    for (int j = 0; j < 4; ++j)
#pragma unroll
      for (int r = 0; r < 4; ++r) acc[i][j][r] = 0.0f;

  const int srow = lane >> 2;
  const int scg  = ((lane & 3) ^ ((lane >> 2) & 3) ^ (lane >> 4)) * 8;
  const int arow = tid >> 1;
  const int q0   = (tid & 1) * 2;
  const int sA   = ((arow & 3) ^ ((arow >> 2) & 3));
  const int fsw  = (qd ^ ((lm ^ (lm >> 2)) & 3)) * 8;

  const int nIter = Kc >> 5;
  for (int it = 0; it < nIter; ++it) {
    const long k0 = k0base + ((long)it << 5);
    {
      const unsigned short* bsrc = Bt + n0 * (size_t)ldb + k0;
#pragma unroll
      for (int q2 = 0; q2 < 2; ++q2) {
        const int rb = wave * 32 + q2 * 16;
        gload_lds16(bsrc + (size_t)(rb + srow) * ldb + scg, &Bs[rb * 32]);
      }
    }
    if (ABF16) {
      const unsigned short* asrc = Ab + m0 * (size_t)lda + k0;
#pragma unroll
      for (int q2 = 0; q2 < 2; ++q2) {
        const int rb = wave * 32 + q2 * 16;
        gload_lds16(asrc + (size_t)(rb + srow) * lda + scg, &As[rb * 32]);
      }
    } else {
      const float* ap = Af + (m0 + arow) * (size_t)lda + k0 + q0 * 8;
      floatx4 f0 = *(const floatx4*)(ap + 0);
      floatx4 f1 = *(const floatx4*)(ap + 4);
      floatx4 f2 = *(const floatx4*)(ap + 8);
      floatx4 f3 = *(const floatx4*)(ap + 12);
      ushortx8 u0, u1;
#pragma unroll
      for (int e = 0; e < 4; ++e) {
        u0[e]     = f2bf(f0[e]);
        u0[e + 4] = f2bf(f1[e]);
        u1[e]     = f2bf(f2[e]);
        u1[e + 4] = f2bf(f3[e]);
      }
      *(ushortx8*)&As[arow * 32 + (q0 ^ sA) * 8]       = u0;
      *(ushortx8*)&As[arow * 32 + ((q0 + 1) ^ sA) * 8] = u1;
    }
    __syncthreads();

    bf16x8 af[4], bfr[4];
#pragma unroll
    for (int i = 0; i < 4; ++i) {
      const int m = wr * 64 + i * 16 + lm;
      af[i] = *(const bf16x8*)&As[m * 32 + fsw];
    }
#pragma unroll
    for (int j = 0; j < 4; ++j) {
      const int n = wc * 64 + j * 16 + lm;
      bfr[j] = *(const bf16x8*)&Bs[n * 32 + fsw];
    }
#pragma unroll
    for (int i = 0; i < 4; ++i)
#pragma unroll
      for (int j = 0; j < 4; ++j)
        acc[i][j] = __builtin_amdgcn_mfma_f32_16x16x32_bf16(af[i], bfr[j], acc[i][j], 0, 0, 0);
    __syncthreads();
  }

  if (EPI == 0) {
#pragma unroll
    for (int j = 0; j < 4; ++j) {
      const long gc = n0 + wc * 64 + j * 16 + lm;
      const float bj = bias[gc];
#pragma unroll
      for (int i = 0; i < 4; ++i) {
        const long gr0 = m0 + wr * 64 + i * 16 + qd * 4;
#pragma unroll
        for (int r = 0; r < 4; ++r)
          C[(gr0 + r) * (size_t)ldc + coloff + gc] = acc[i][j][r] + bj;
      }
    }
  } else if (EPI == 2) {
#pragma unroll
    for (int j = 0; j < 4; ++j) {
      const long gc = n0 + wc * 64 + j * 16 + lm;
      const float bj = (blockIdx.z == 0) ? bias[gc] : 0.0f;
#pragma unroll
      for (int i = 0; i < 4; ++i) {
        const long gr0 = m0 + wr * 64 + i * 16 + qd * 4;
#pragma unroll
        for (int r = 0; r < 4; ++r)
          atomicAdd(&C[(gr0 + r) * (size_t)ldc + coloff + gc], acc[i][j][r] + bj);
      }
    }
  } else {
    float vj[4], bkj[4];
    int gcj[4];
#pragma unroll
    for (int j = 0; j < 4; ++j) {
      gcj[j] = (int)(n0 + wc * 64 + j * 16 + lm);
      vj[j]  = vvec[gcj[j]];
      bkj[j] = bkv[gcj[j]];
    }
    const int m0i = (int)m0;
#pragma unroll
    for (int i = 0; i < 4; ++i) {
#pragma unroll
      for (int r = 0; r < 4; ++r) {
        const int grow = m0i + wr * 64 + i * 16 + qd * 4 + r;
        int brow;
        if (Lrows == 196) brow = (int)((unsigned)(grow * 85599u) >> 24);
        else              brow = grow / Lrows;
        const float* qrow = qv + (size_t)brow * Hdim;
        float s = 0.0f;
#pragma unroll
        for (int j = 0; j < 4; ++j)
          s += fast_tanh(qrow[gcj[j]] + bkj[j] + acc[i][j][r]) * vj[j];
        s += __shfl_xor(s, 1, 64);
        s += __shfl_xor(s, 2, 64);
        s += __shfl_xor(s, 4, 64);
        s += __shfl_xor(s, 8, 64);
        if (lm == 0) atomicAdd(&scores[grow], s);
      }
    }
  }
}

// --------------------------- prep kernels ----------------------------------
__global__ void transpose_f32_bf16(const float* __restrict__ in,
                                   unsigned short* __restrict__ out, int R, int C) {
  __shared__ float tile[32][33];
  const int c0 = blockIdx.x * 32, r0 = blockIdx.y * 32;
  const int tx = threadIdx.x, ty = threadIdx.y;  // (32,8)
#pragma unroll
  for (int yy = 0; yy < 4; ++yy)
    tile[ty + 8 * yy][tx] = in[(size_t)(r0 + ty + 8 * yy) * C + c0 + tx];
  __syncthreads();
#pragma unroll
  for (int yy = 0; yy < 4; ++yy)
    out[(size_t)(c0 + ty + 8 * yy) * R + r0 + tx] = f2bf(tile[tx][ty + 8 * yy]);
}

__global__ void convert_bf16(const float* __restrict__ in,
                             unsigned short* __restrict__ out, int n4) {
  const int idx = blockIdx.x * blockDim.x + threadIdx.x;
  if (idx < n4) {
    floatx4 f = *(const floatx4*)(in + 4 * (size_t)idx);
    ushortx4 u;
#pragma unroll
    for (int e = 0; e < 4; ++e) u[e] = f2bf(f[e]);
    *(ushortx4*)(out + 4 * (size_t)idx) = u;
  }
}

__global__ void gather_emb(const int* __restrict__ inputs, const float* __restrict__ emb,
                           float* __restrict__ rnn_in, int E, int ldr) {
  const int b = blockIdx.x, t = threadIdx.x;
  const int row = inputs[b];
  for (int e = t; e < E; e += 256)
    rnn_in[(size_t)b * ldr + e] = emb[(size_t)row * E + e];
}

// ----------------------------- softmax over L ------------------------------
__global__ __launch_bounds__(256) void softmax_w(
    const float* __restrict__ scores, const float* __restrict__ bv,
    float* __restrict__ weights, int L)
{
  __shared__ float red[8];
  const int b = blockIdx.x, t = threadIdx.x;
  const int wave = t >> 6;
  float s = (t < L) ? scores[(size_t)b * L + t] + bv[0] : -3.4e38f;
  float m = s;
  for (int o = 32; o > 0; o >>= 1) m = fmaxf(m, __shfl_xor(m, o, 64));
  if ((t & 63) == 0) red[wave] = m;
  __syncthreads();
  m = fmaxf(fmaxf(red[0], red[1]), fmaxf(red[2], red[3]));
  float e = (t < L) ? __expf(s - m) : 0.0f;
  float sum = e;
  for (int o = 32; o > 0; o >>= 1) sum += __shfl_xor(sum, o, 64);
  if ((t & 63) == 0) red[4 + wave] = sum;
  __syncthreads();
  sum = red[4] + red[5] + red[6] + red[7];
  if (t < L) weights[(size_t)b * L + t] = e / sum;
}

// ------------------- context[b,k] = sum_l w[b,l]*keys[b,l,k] ---------------
template <bool KB16>
__global__ __launch_bounds__(256) void context_k(
    const float* __restrict__ weights, const unsigned short* __restrict__ keys16,
    const float* __restrict__ keysf, float* __restrict__ context, int L, int K)
{
  __shared__ float w[256];
  const int b = blockIdx.x, t = threadIdx.x;
  if (t < L) w[t] = weights[(size_t)b * L + t];
  __syncthreads();
  const int col0 = blockIdx.y * 512 + t * 2;
  float a0 = 0.0f, a1 = 0.0f;
  if (KB16) {
    const unsigned short* kp = keys16 + (size_t)b * L * K + col0;
#pragma unroll 4
    for (int l = 0; l < L; ++l) {
      const unsigned int u = *(const unsigned int*)(kp + (size_t)l * K);
      a0 += w[l] * bf2f((unsigned short)(u & 0xffff));
      a1 += w[l] * bf2f((unsigned short)(u >> 16));
    }
  } else {
    const float* kp = keysf + (size_t)b * L * K + col0;
#pragma unroll 4
    for (int l = 0; l < L; ++l) {
      a0 += w[l] * kp[(size_t)l * K];
      a1 += w[l] * kp[(size_t)l * K + 1];
    }
  }
  context[(size_t)b * K + col0]     = a0;
  context[(size_t)b * K + col0 + 1] = a1;
}

// ------------------------------- GRU cell ----------------------------------
__global__ void gru_kernel(const float* __restrict__ gi, const float* __restrict__ gh,
                           const float* __restrict__ hidden, float* __restrict__ hnew, int H) {
  const int idx = blockIdx.x * blockDim.x + threadIdx.x;  // B*H
  const int b = idx / H, h = idx % H;
  const size_t base = (size_t)b * 3 * H;
  const float ir = gi[base + h], iz = gi[base + H + h], inn = gi[base + 2 * H + h];
  const float hr = gh[base + h], hz = gh[base + H + h], hn = gh[base + 2 * H + h];
  const float r = 1.0f / (1.0f + __expf(-(ir + hr)));
  const float z = 1.0f / (1.0f + __expf(-(iz + hz)));
  const float n = tanhf(inn + r * hn);
  const float hv = hidden[(size_t)b * H + h];
  hnew[(size_t)b * H + h] = (1.0f - z) * n + z * hv;
}

// ---------------------------------------------------------------------------
extern "C" void kernel_launch(void* const* d_in, const int* in_sizes, int n_in,
                              void* d_out, int out_size, void* d_ws, size_t ws_size,
                              hipStream_t stream) {
  constexpr int V = 32000, E = 512, H = 1024, KD = 2048, L = 196, B = 256;
  constexpr int G3 = 3 * H;   // 3072
  constexpr int EH = E + H;   // 1536

  const int*   inputs = (const int*)d_in[0];
  const float* hidden = (const float*)d_in[1];
  const float* keys   = (const float*)d_in[2];
  const float* emb    = (const float*)d_in[3];
  const float* Wq     = (const float*)d_in[4];
  const float* bq     = (const float*)d_in[5];
  const float* Wk     = (const float*)d_in[6];
  const float* bk     = (const float*)d_in[7];
  const float* vvec   = (const float*)d_in[8];
  const float* bv     = (const float*)d_in[9];
  const float* fc0_W  = (const float*)d_in[10];
  const float* fc0_b  = (const float*)d_in[11];
  const float* W_ih   = (const float*)d_in[12];
  const float* W_hh   = (const float*)d_in[13];
  const float* b_ih   = (const float*)d_in[14];
  const float* b_hh   = (const float*)d_in[15];
  const float* fc1_W  = (const float*)d_in[16];
  const float* fc1_b  = (const float*)d_in[17];

  float* logits  = (float*)d_out;
  float* hnew    = logits + (size_t)B * V;
  float* weights = hnew + (size_t)B * H;

  char* ws = (char*)d_ws;
  size_t off = 0;
  auto bump = [&off](size_t bytes) {
    size_t p = off;
    off += (bytes + 255) & ~(size_t)255;
    return p;
  };
  unsigned short* WqT   = (unsigned short*)(ws + bump((size_t)H * H * 2));
  unsigned short* WkT   = (unsigned short*)(ws + bump((size_t)H * KD * 2));
  unsigned short* fc0T  = (unsigned short*)(ws + bump((size_t)H * KD * 2));
  unsigned short* fc1T  = (unsigned short*)(ws + bump((size_t)V * H * 2));
  unsigned short* Wih16 = (unsigned short*)(ws + bump((size_t)G3 * EH * 2));
  unsigned short* Whh16 = (unsigned short*)(ws + bump((size_t)G3 * H * 2));
  float* qbuf    = (float*)(ws + bump((size_t)B * H * 4));
  float* scoresb = (float*)(ws + bump((size_t)B * L * 4));
  float* context = (float*)(ws + bump((size_t)B * KD * 4));
  float* rnn_in  = (float*)(ws + bump((size_t)B * EH * 4));
  float* gi      = (float*)(ws + bump((size_t)B * G3 * 4));
  float* gh      = (float*)(ws + bump((size_t)B * G3 * 4));
  unsigned short* keys16 = (unsigned short*)(ws + bump((size_t)B * L * KD * 2));
  const bool useK16 = (off <= ws_size);  // constant across calls -> graph-safe

  // split-K targets must start from zero (ws is re-poisoned before each call)
  hipMemsetAsync(scoresb, 0, (size_t)B * L * 4, stream);
  hipMemsetAsync(qbuf, 0, (size_t)B * H * 4, stream);
  hipMemsetAsync(rnn_in, 0, (size_t)B * EH * 4, stream);
  hipMemsetAsync(gi, 0, (size_t)B * G3 * 4, stream);
  hipMemsetAsync(gh, 0, (size_t)B * G3 * 4, stream);

  const dim3 tb(32, 8);
  transpose_f32_bf16<<<dim3(H / 32, H / 32), tb, 0, stream>>>(Wq, WqT, H, H);
  transpose_f32_bf16<<<dim3(H / 32, KD / 32), tb, 0, stream>>>(Wk, WkT, KD, H);
  transpose_f32_bf16<<<dim3(H / 32, KD / 32), tb, 0, stream>>>(fc0_W, fc0T, KD, H);
  transpose_f32_bf16<<<dim3(V / 32, H / 32), tb, 0, stream>>>(fc1_W, fc1T, H, V);
  convert_bf16<<<(G3 * EH / 4 + 255) / 256, 256, 0, stream>>>(W_ih, Wih16, G3 * EH / 4);
  convert_bf16<<<(G3 * H / 4 + 255) / 256, 256, 0, stream>>>(W_hh, Whh16, G3 * H / 4);
  if (useK16) {
    const int n4 = B * L * KD / 4;
    convert_bf16<<<(n4 + 255) / 256, 256, 0, stream>>>(keys, keys16, n4);
  }

  gather_emb<<<B, 256, 0, stream>>>(inputs, emb, rnn_in, E, EH);

  // q = hidden @ Wq + bq   (split-K x4 -> 64 blocks instead of 16)
  gemm_bt<2, false, false><<<dim3(H / 128, B / 128, 4), 256, 0, stream>>>(
      hidden, nullptr, H, WqT, H, H / 4, qbuf, H, 0, bq,
      nullptr, nullptr, nullptr, nullptr, 0, 0);

  // scores[b*L+l] = tanh(q[b]+bk+keys[b,l]@Wk) . v   (the 210 GFLOP GEMM)
  if (useK16)
    gemm_scores_8ph<<<dim3((H / 256) * ((B * L) / 256), 1, 1), 512, 0, stream>>>(
        keys16, WkT, qbuf, bk, vvec, scoresb);
  else
    gemm_bt<1, false, true><<<dim3(H / 128, (B * L) / 128, 1), 256, 0, stream>>>(
        keys, nullptr, KD, WkT, KD, KD, nullptr, 0, 0, nullptr,
        qbuf, bk, vvec, scoresb, L, H);

  softmax_w<<<B, 256, 0, stream>>>(scoresb, bv, weights, L);

  if (useK16)
    context_k<true><<<dim3(B, KD / 512), 256, 0, stream>>>(weights, keys16, nullptr,
                                                           context, L, KD);
  else
    context_k<false><<<dim3(B, KD / 512), 256, 0, stream>>>(weights, nullptr, keys,
                                                            context, L, KD);

  // rnn_in[:, E:] = context @ fc0_W + fc0_b   (split-K x4)
  gemm_bt<2, false, false><<<dim3(H / 128, B / 128, 4), 256, 0, stream>>>(
      context, nullptr, KD, fc0T, KD, KD / 4, rnn_in, EH, E, fc0_b,
      nullptr, nullptr, nullptr, nullptr, 0, 0);

  // gi = rnn_in @ W_ih^T + b_ih   (split-K x4)
  gemm_bt<2, false, false><<<dim3(G3 / 128, B / 128, 4), 256, 0, stream>>>(
      rnn_in, nullptr, EH, Wih16, EH, EH / 4, gi, G3, 0, b_ih,
      nullptr, nullptr, nullptr, nullptr, 0, 0);

  // gh = hidden @ W_hh^T + b_hh   (split-K x4)
  gemm_bt<2, false, false><<<dim3(G3 / 128, B / 128, 4), 256, 0, stream>>>(
      hidden, nullptr, H, Whh16, H, H / 4, gh, G3, 0, b_hh,
      nullptr, nullptr, nullptr, nullptr, 0, 0);

  gru_kernel<<<(B * H) / 256, 256, 0, stream>>>(gi, gh, hidden, hnew, H);

  // logits = h_new @ fc1_W + fc1_b  (500 blocks, no split needed)
  gemm_bt<0, false, false><<<dim3(V / 128, B / 128, 1), 256, 0, stream>>>(
      hnew, nullptr, H, fc1T, H, H, logits, V, 0, fc1_b,
      nullptr, nullptr, nullptr, nullptr, 0, 0);
}